// Round 9
// baseline (505.618 us; speedup 1.0000x reference)
//
#include <hip/hip_runtime.h>
#include <math.h>

#define NTOT   32768
#define NSCN   16
#define NPS    2048
#define KK     16
#define CD     128
#define HD     256
#define GC     32      // grid cells per axis
#define QCAP   96      // survivor queue per query (overflow -> exact fallback)
#define QSTR   97      // queue stride (u64) to stagger LDS banks

typedef __attribute__((ext_vector_type(8))) short short8v;   // bf16x8 MFMA frag
typedef __attribute__((ext_vector_type(4))) float f32x4;     // MFMA accumulator
typedef unsigned long long u64;

__device__ __forceinline__ ushort f2bf(float f) {            // RNE f32->bf16
    uint u = __float_as_uint(f);
    u += 0x7FFFu + ((u >> 16) & 1u);
    return (ushort)(u >> 16);
}
__device__ __forceinline__ float bf2f(ushort h) {
    return __uint_as_float(((uint)h) << 16);
}

// ---------------------------------------------------------------------------
// K1: fused grid build (blocks 0..15, counting sort per scene) + prep
// ---------------------------------------------------------------------------
__global__ __launch_bounds__(256) void build_prep_kernel(
    const float* __restrict__ pos,
    float2* __restrict__ spos, int* __restrict__ soidx,
    int* __restrict__ cstart, float4* __restrict__ bboxg,
    const float* __restrict__ w, const float* __restrict__ Wc,
    const float* __restrict__ W1, const float* __restrict__ W2,
    ushort* __restrict__ wbf, ushort* __restrict__ WcT,
    ushort* __restrict__ W1T, ushort* __restrict__ W2T)
{
    __shared__ int hist[GC * GC];
    __shared__ int scan_[GC * GC];
    __shared__ int part[256];
    __shared__ float4 wred[4];
    __shared__ float4 bbS;

    if (blockIdx.x >= 16) {
        const int n_wb = NTOT * CD;
        const int n_wc = CD * CD;
        const int n_w1 = HD * CD;
        const int n_w2 = 144 * HD;
        const int total = n_wb + n_wc + n_w1 + n_w2;
        const int stride = (gridDim.x - 16) * 256;
        for (int t = (blockIdx.x - 16) * 256 + threadIdx.x; t < total; t += stride) {
            if (t < n_wb) {
                wbf[t] = f2bf(w[t]);
            } else if (t < n_wb + n_wc) {
                const int e = t - n_wb; const int n = e >> 7, k = e & 127;
                WcT[e] = f2bf(Wc[k * CD + n]);
            } else if (t < n_wb + n_wc + n_w1) {
                const int e = t - n_wb - n_wc; const int n = e >> 7, k = e & 127;
                W1T[e] = f2bf(W1[k * HD + n]);
            } else {
                const int e = t - n_wb - n_wc - n_w1; const int n = e >> 8, k = e & 255;
                W2T[e] = (n < 130) ? f2bf(W2[k * 130 + n]) : (ushort)0;
            }
        }
        return;
    }

    const int s = blockIdx.x;
    const float2* gp = (const float2*)pos + s * NPS;

    float xmn = 3e38f, xmx = -3e38f, ymn = 3e38f, ymx = -3e38f;
    for (int i = threadIdx.x; i < NPS; i += 256) {
        const float2 p = gp[i];
        xmn = fminf(xmn, p.x); xmx = fmaxf(xmx, p.x);
        ymn = fminf(ymn, p.y); ymx = fmaxf(ymx, p.y);
    }
#pragma unroll
    for (int off = 1; off < 64; off <<= 1) {
        xmn = fminf(xmn, __shfl_xor(xmn, off));
        xmx = fmaxf(xmx, __shfl_xor(xmx, off));
        ymn = fminf(ymn, __shfl_xor(ymn, off));
        ymx = fmaxf(ymx, __shfl_xor(ymx, off));
    }
    if ((threadIdx.x & 63) == 0) wred[threadIdx.x >> 6] = make_float4(xmn, xmx, ymn, ymx);
    __syncthreads();
    if (threadIdx.x == 0) {
        float a = wred[0].x, bx = wred[0].y, c = wred[0].z, d = wred[0].w;
        for (int i = 1; i < 4; ++i) {
            a = fminf(a, wred[i].x); bx = fmaxf(bx, wred[i].y);
            c = fminf(c, wred[i].z); d  = fmaxf(d, wred[i].w);
        }
        const float hx = fmaxf(bx - a, 1e-6f) * (1.0f / GC);
        const float hy = fmaxf(d - c, 1e-6f) * (1.0f / GC);
        bbS = make_float4(a, c, hx, hy);
        bboxg[s] = bbS;
    }
    __syncthreads();
    const float bxm = bbS.x, bym = bbS.y;
    const float ihx = 1.0f / bbS.z, ihy = 1.0f / bbS.w;

    for (int i = threadIdx.x; i < GC * GC; i += 256) hist[i] = 0;
    __syncthreads();
    for (int i = threadIdx.x; i < NPS; i += 256) {
        const float2 p = gp[i];
        int cx = (int)((p.x - bxm) * ihx); cx = cx < 0 ? 0 : (cx > GC - 1 ? GC - 1 : cx);
        int cy = (int)((p.y - bym) * ihy); cy = cy < 0 ? 0 : (cy > GC - 1 ? GC - 1 : cy);
        atomicAdd(&hist[cy * GC + cx], 1);
    }
    __syncthreads();
    {
        const int base = threadIdx.x * 4;
        int run = 0;
#pragma unroll
        for (int j = 0; j < 4; ++j) run += hist[base + j];
        part[threadIdx.x] = run;
        __syncthreads();
        if (threadIdx.x == 0) {
            int acc = 0;
            for (int t = 0; t < 256; ++t) { const int v = part[t]; part[t] = acc; acc += v; }
        }
        __syncthreads();
        run = part[threadIdx.x];
#pragma unroll
        for (int j = 0; j < 4; ++j) { const int h = hist[base + j]; scan_[base + j] = run; run += h; }
    }
    __syncthreads();
    for (int i = threadIdx.x; i < GC * GC; i += 256) cstart[s * (GC * GC + 1) + i] = scan_[i];
    if (threadIdx.x == 0) cstart[s * (GC * GC + 1) + GC * GC] = NPS;
    __syncthreads();
    for (int i = threadIdx.x; i < NPS; i += 256) {
        const float2 p = gp[i];
        int cx = (int)((p.x - bxm) * ihx); cx = cx < 0 ? 0 : (cx > GC - 1 ? GC - 1 : cx);
        int cy = (int)((p.y - bym) * ihy); cy = cy < 0 ? 0 : (cy > GC - 1 ? GC - 1 : cy);
        const int d = atomicAdd(&scan_[cy * GC + cx], 1);
        spos[s * NPS + d] = p;
        soidx[s * NPS + d] = i;
    }
}

// ---------------------------------------------------------------------------
// K2: fused exact-KNN (count/filter/rank selection) + MLP (MFMA), 2:1.
// KNN per query (8 lanes): ring expansion with bucket counters (branchless),
// exact count stop; T = min(tightest bucket bound, max per-lane 2nd-min) >= d16;
// append survivors (d2<=T) to LDS queue; rank phase = n^2 strict-key compares
// -> output slot = rank  (== jax stable top_k). Overflow -> exact fallback
// (per-lane top-16 insert + 3-level merge, R7-proven).
// ---------------------------------------------------------------------------
__global__ __launch_bounds__(256, 3) void knn_mlp_kernel(
    const float2* __restrict__ spos, const int* __restrict__ soidx,
    const int* __restrict__ cstart, const float4* __restrict__ bboxg,
    int* __restrict__ idx_out, float* __restrict__ ker_out, float* __restrict__ den_out,
    const ushort* __restrict__ wbf, const float* __restrict__ w, const float* __restrict__ pos,
    const ushort* __restrict__ W1T, const float* __restrict__ b1,
    const ushort* __restrict__ W2T, const float* __restrict__ b2,
    float* __restrict__ out_pos, float* __restrict__ out_w)
{
    __shared__ __align__(16) char smem[53512];
    const int b = blockIdx.x;
    const int m3 = b % 3;

    if (m3 < 2) {
        // =================== KNN path ===================
        const int kb = (b / 3) * 2 + m3;           // 0..1023
        float2* sp  = (float2*)smem;               // 16 KB
        int*    oix = (int*)(smem + 16384);        // 8 KB
        int*    cs  = (int*)(smem + 24576);        // 4.1 KB
        u64*    qkA = (u64*)(smem + 28680);        // 32 queries x QSTR u64
        const int scene = kb >> 6;                 // 64 blocks per scene
        const int sbase = scene * NPS;
        for (int i = threadIdx.x; i < NPS; i += 256) { sp[i] = spos[sbase + i]; oix[i] = soidx[sbase + i]; }
        for (int i = threadIdx.x; i < GC * GC + 1; i += 256) cs[i] = cstart[scene * (GC * GC + 1) + i];
        __syncthreads();

        const float4 bb = bboxg[scene];
        const float ihx = 1.0f / bb.z, ihy = 1.0f / bb.w;
        const int p = threadIdx.x >> 3;            // query slot 0..31
        const int r = threadIdx.x & 7;             // octet lane
        const int qi = (kb & 63) * 32 + p;         // sorted-order point index
        const float2 my = sp[qi];
        u64* qk = qkA + p * QSTR;
        int cx = (int)((my.x - bb.x) * ihx); cx = cx < 0 ? 0 : (cx > GC - 1 ? GC - 1 : cx);
        int cy = (int)((my.y - bb.y) * ihy); cy = cy < 0 ? 0 : (cy > GC - 1 ? GC - 1 : cy);

        const float hmin = fminf(bb.z, bb.w);
        float tj[8];
#pragma unroll
        for (int j = 0; j < 8; ++j) { const float x = (float)(j + 1) * hmin; tj[j] = x * x; }
        int cnt[8];
#pragma unroll
        for (int j = 0; j < 8; ++j) cnt[j] = 0;
        float m1 = 3.0e38f, m2 = 3.0e38f;

#define CAND(E) { \
    const float2 c2 = sp[E]; \
    const float ddx = c2.x - my.x, ddy = c2.y - my.y; \
    const float d2 = __fadd_rn(__fmul_rn(ddx, ddx), __fmul_rn(ddy, ddy)); \
    _Pragma("unroll") \
    for (int j = 0; j < 8; ++j) cnt[j] += (d2 <= tj[j]) ? 1 : 0; \
    m2 = fminf(m2, fmaxf(m1, d2)); m1 = fminf(m1, d2); }

        // ---- initial square R=1, rank-balanced 8 ways ----
        int xl = cx - 1 < 0 ? 0 : cx - 1, xh = cx + 1 > GC - 1 ? GC - 1 : cx + 1;
        int yl = cy - 1 < 0 ? 0 : cy - 1, yh = cy + 1 > GC - 1 ? GC - 1 : cy + 1;
        {
            int c = 0;
            for (int y = yl + r; y <= yh; y += 8) c += cs[y * GC + xh + 1] - cs[y * GC + xl];
            c += __shfl_xor(c, 1); c += __shfl_xor(c, 2); c += __shfl_xor(c, 4);
            const int t0 = (r * c) >> 3, t1 = ((r + 1) * c) >> 3;
            if (t0 < t1) {
                int y = yl, acc = 0;
                int rowc = cs[y * GC + xh + 1] - cs[y * GC + xl];
                while (acc + rowc <= t0) { acc += rowc; ++y; rowc = cs[y * GC + xh + 1] - cs[y * GC + xl]; }
                int e = cs[y * GC + xl] + (t0 - acc), eend = cs[y * GC + xh + 1];
                for (int t = t0; t < t1; ++t) {
                    while (e >= eend) { ++y; e = cs[y * GC + xl]; eend = cs[y * GC + xh + 1]; }
                    CAND(e); ++e;
                }
            }
        }

        // ---- expansion: exact bucket-count stop ----
        int R = 1;
        while (true) {
            if (xl == 0 && yl == 0 && xh == GC - 1 && yh == GC - 1) break;
            const float px = my.x - bb.x, py = my.y - bb.y;
            float g = 3e38f;
            if (xl > 0)      g = fminf(g, px - (float)xl * bb.z);
            if (xh < GC - 1) g = fminf(g, (float)(xh + 1) * bb.z - px);
            if (yl > 0)      g = fminf(g, py - (float)yl * bb.w);
            if (yh < GC - 1) g = fminf(g, (float)(yh + 1) * bb.w - py);
            g -= 1e-4f;
            if (g > 0.f) {
                int jg = (int)(g / hmin); jg = jg > 8 ? 8 : jg;
                if (jg >= 1) {
                    int cc = cnt[0];
#pragma unroll
                    for (int j = 1; j < 8; ++j) cc = (jg >= j + 1) ? cnt[j] : cc;
                    cc += __shfl_xor(cc, 1); cc += __shfl_xor(cc, 2); cc += __shfl_xor(cc, 4);
                    if (cc >= 16) break;            // >=16 proven within scanned region
                }
            }
            ++R;
            const int nxl = cx - R < 0 ? 0 : cx - R, nxh = cx + R > GC - 1 ? GC - 1 : cx + R;
            const int nyl = cy - R < 0 ? 0 : cy - R, nyh = cy + R > GC - 1 ? GC - 1 : cy + R;
            if (r < 4) {                            // new top/bottom row, halved by rank
                const int y = (r < 2) ? cy - R : cy + R;
                if (y >= 0 && y <= GC - 1) {
                    const int e0 = cs[y * GC + nxl], e1 = cs[y * GC + nxh + 1];
                    const int n = e1 - e0, h = r & 1;
                    const int es = e0 + ((n * h) >> 1), ee = e0 + ((n * (h + 1)) >> 1);
                    for (int e = es; e < ee; ++e) CAND(e);
                }
            } else {                                // new left/right col, y-parity split
                const int x = (r < 6) ? cx - R : cx + R;
                if (x >= 0 && x <= GC - 1) {
                    const int ylc = nyl + ((cy - R >= 0) ? 1 : 0);
                    const int yhc = nyh - ((cy + R <= GC - 1) ? 1 : 0);
                    for (int y = ylc + (r & 1); y <= yhc; y += 2) {
                        const int c0 = y * GC + x;
                        const int e1_ = cs[c0 + 1];
                        for (int e = cs[c0]; e < e1_; ++e) CAND(e);
                    }
                }
            }
            xl = nxl; xh = nxh; yl = nyl; yh = nyh;
        }
#undef CAND

        // ---- T = min(tightest bucket bound with >=16, octet-max 2nd-min) ----
        float Tb = 3.0e38f;
#pragma unroll
        for (int j = 7; j >= 0; --j) {
            int v = cnt[j];
            v += __shfl_xor(v, 1); v += __shfl_xor(v, 2); v += __shfl_xor(v, 4);
            Tb = (v >= 16) ? tj[j] : Tb;
        }
        float Tub = m2;
        Tub = fmaxf(Tub, __shfl_xor(Tub, 1));
        Tub = fmaxf(Tub, __shfl_xor(Tub, 2));
        Tub = fmaxf(Tub, __shfl_xor(Tub, 4));
        const float T = fminf(Tb, Tub);

        // ---- append survivors (d2 <= T) to queue, lockstep ballot-compact ----
        int n = 0;
        {
            int c = 0;
            for (int y = yl + r; y <= yh; y += 8) c += cs[y * GC + xh + 1] - cs[y * GC + xl];
            c += __shfl_xor(c, 1); c += __shfl_xor(c, 2); c += __shfl_xor(c, 4);
            const int t0 = (r * c) >> 3, t1 = ((r + 1) * c) >> 3;
            const int len = t1 - t0;
            int y = yl, e = 0, eend = 0;
            if (len > 0) {
                int acc = 0;
                int rowc = cs[y * GC + xh + 1] - cs[y * GC + xl];
                while (acc + rowc <= t0) { acc += rowc; ++y; rowc = cs[y * GC + xh + 1] - cs[y * GC + xl]; }
                e = cs[y * GC + xl] + (t0 - acc); eend = cs[y * GC + xh + 1];
            }
            const int tmax = (c + 7) >> 3;
            for (int t = 0; t < tmax; ++t) {
                bool keep = false; uint d2b = 0; int oe = 0;
                if (t < len) {
                    while (e >= eend) { ++y; e = cs[y * GC + xl]; eend = cs[y * GC + xh + 1]; }
                    const float2 c2 = sp[e];
                    const float ddx = c2.x - my.x, ddy = c2.y - my.y;
                    const float d2 = __fadd_rn(__fmul_rn(ddx, ddx), __fmul_rn(ddy, ddy));
                    keep = (d2 <= T);
                    d2b = __float_as_uint(d2);
                    oe = oix[e];
                    ++e;
                }
                const u64 bal = __ballot(keep);
                const uint m8 = (uint)((bal >> (threadIdx.x & 56)) & 0xFFull);
                if (keep) {
                    const int off = n + (int)__popc(m8 & ((1u << r) - 1u));
                    if (off < QCAP) qk[off] = (((u64)d2b) << 32) | (uint)oe;
                }
                n += (int)__popc(m8);
            }
        }

        const int gq = sbase + oix[qi];             // output row = ORIGINAL index

        if (n <= QCAP) {
            // ---- rank phase: slot = #{keys < mine}; exact stable top-16 ----
            float den = 0.f;
            for (int e = r; e < n; e += 8) {
                const u64 ke = qk[e];
                int rank = 0;
                for (int j = 0; j < n; ++j) rank += (qk[j] < ke) ? 1 : 0;
                if (rank < 16) {
                    const float d2 = __uint_as_float((uint)(ke >> 32));
                    const float kv = expf(-2.0f * d2);
                    idx_out[gq * KK + rank] = sbase + (int)(ke & 0xFFFFFFFFULL);
                    ker_out[gq * KK + rank] = kv;
                    den += kv;
                }
            }
            den += __shfl_xor(den, 1); den += __shfl_xor(den, 2); den += __shfl_xor(den, 4);
            if (r == 0) den_out[gq] = den;
        } else {
            // ---- cold exact fallback: per-lane top-16 + 3-level merge ----
            u64 key[16];
#pragma unroll
            for (int s_ = 0; s_ < 16; ++s_) key[s_] = ~0ULL;
            {
                int c = 0;
                for (int y = yl + r; y <= yh; y += 8) c += cs[y * GC + xh + 1] - cs[y * GC + xl];
                c += __shfl_xor(c, 1); c += __shfl_xor(c, 2); c += __shfl_xor(c, 4);
                const int t0 = (r * c) >> 3, t1 = ((r + 1) * c) >> 3;
                if (t0 < t1) {
                    int y = yl, acc = 0;
                    int rowc = cs[y * GC + xh + 1] - cs[y * GC + xl];
                    while (acc + rowc <= t0) { acc += rowc; ++y; rowc = cs[y * GC + xh + 1] - cs[y * GC + xl]; }
                    int e = cs[y * GC + xl] + (t0 - acc), eend = cs[y * GC + xh + 1];
                    for (int t = t0; t < t1; ++t) {
                        while (e >= eend) { ++y; e = cs[y * GC + xl]; eend = cs[y * GC + xh + 1]; }
                        {
                            const float2 c2 = sp[e];
                            const float ddx = c2.x - my.x, ddy = c2.y - my.y;
                            const float d2 = __fadd_rn(__fmul_rn(ddx, ddx), __fmul_rn(ddy, ddy));
                            const uint d2b = __float_as_uint(d2);
                            if ((u64)d2b <= (key[15] >> 32)) {
                                u64 ck = (((u64)d2b) << 32) | (uint)oix[e];
#pragma unroll
                                for (int s_ = 0; s_ < 16; ++s_) {
                                    const bool sm_ = ck < key[s_]; const u64 o_ = key[s_];
                                    key[s_] = sm_ ? ck : o_; ck = sm_ ? o_ : ck;
                                }
                            }
                        }
                        ++e;
                    }
                }
            }
#pragma unroll
            for (int lvl = 1; lvl <= 4; lvl <<= 1) {
                u64 tmp[16];
#pragma unroll
                for (int s_ = 0; s_ < 16; ++s_) {
                    const uint lo = (uint)__shfl_xor((int)(uint)(key[s_] & 0xFFFFFFFFULL), lvl);
                    const uint hi = (uint)__shfl_xor((int)(uint)(key[s_] >> 32), lvl);
                    tmp[s_] = (((u64)hi) << 32) | lo;
                }
#pragma unroll
                for (int s_ = 0; s_ < 16; ++s_) {
                    u64 ck = tmp[s_];
                    if (ck < key[15]) {
#pragma unroll
                        for (int t2 = 0; t2 < 16; ++t2) {
                            const bool sm = ck < key[t2];
                            const u64 o = key[t2];
                            key[t2] = sm ? ck : o;
                            ck      = sm ? o  : ck;
                        }
                    }
                }
            }
            if (r == 0) {
                int iv[16]; float kv[16]; float den = 0.f;
#pragma unroll
                for (int s_ = 0; s_ < 16; ++s_) {
                    const float d2 = __uint_as_float((uint)(key[s_] >> 32));
                    kv[s_] = expf(-2.0f * d2);
                    den += kv[s_];
                    iv[s_] = sbase + (int)(key[s_] & 0xFFFFFFFFULL);
                }
                int4*   ip4 = (int4*)(idx_out + gq * KK);
                float4* kp4 = (float4*)(ker_out + gq * KK);
#pragma unroll
                for (int s_ = 0; s_ < 4; ++s_) {
                    ip4[s_] = make_int4(iv[4*s_], iv[4*s_+1], iv[4*s_+2], iv[4*s_+3]);
                    kp4[s_] = make_float4(kv[4*s_], kv[4*s_+1], kv[4*s_+2], kv[4*s_+3]);
                }
                den_out[gq] = den;
            }
        }
        return;
    }

    // =================== MLP path ===================
    {
        const int mb = b / 3;                      // 0..511
        char* hS = smem;                           // 64 rows x 256 bf16 = 32 KB
        const int l = threadIdx.x & 63, wave = threadIdx.x >> 6;
        const int a = l & 15, g = l >> 4;
        const int m0 = wave * 16;
        const int rbase = mb * 64;
        const f32x4 z4 = {0.f, 0.f, 0.f, 0.f};

        f32x4 acc1[16];
#pragma unroll
        for (int nt = 0; nt < 16; ++nt) acc1[nt] = z4;
#pragma unroll
        for (int ks = 0; ks < 4; ++ks) {
            const short8v av = *(const short8v*)(wbf + (size_t)(rbase + m0 + a) * CD + ks * 32 + g * 8);
#pragma unroll
            for (int nt = 0; nt < 16; ++nt) {
                const short8v bv = *(const short8v*)(W1T + (nt * 16 + a) * CD + ks * 32 + g * 8);
                acc1[nt] = __builtin_amdgcn_mfma_f32_16x16x32_bf16(av, bv, acc1[nt], 0, 0, 0);
            }
        }
#pragma unroll
        for (int nt = 0; nt < 16; ++nt) {
            const float b1v = b1[nt * 16 + a];
#pragma unroll
            for (int rr = 0; rr < 4; ++rr) {
                const float hv = fmaxf(acc1[nt][rr] + b1v, 0.f);
                const int row = m0 + 4 * g + rr;
                int byte = row * 512 + (nt * 16 + a) * 2;
                byte ^= ((row & 7) << 4);
                *(ushort*)(hS + byte) = f2bf(hv);
            }
        }
        __syncthreads();

        f32x4 acc2[9];
#pragma unroll
        for (int nt = 0; nt < 9; ++nt) acc2[nt] = z4;
#pragma unroll
        for (int ks = 0; ks < 8; ++ks) {
            const int row = m0 + a;
            int byte = row * 512 + (ks * 32 + g * 8) * 2;
            byte ^= ((row & 7) << 4);
            const short8v av = *(const short8v*)(hS + byte);
#pragma unroll
            for (int nt = 0; nt < 9; ++nt) {
                const short8v bv = *(const short8v*)(W2T + (nt * 16 + a) * HD + ks * 32 + g * 8);
                acc2[nt] = __builtin_amdgcn_mfma_f32_16x16x32_bf16(av, bv, acc2[nt], 0, 0, 0);
            }
        }
#pragma unroll
        for (int nt = 0; nt < 9; ++nt) {
            const int col = nt * 16 + a;
            const float b2v = (col < 130) ? b2[col] : 0.f;
#pragma unroll
            for (int rr = 0; rr < 4; ++rr) {
                const int rowg = rbase + m0 + 4 * g + rr;
                const float dv = acc2[nt][rr] + b2v;
                if (col >= 2 && col < 130) {
                    out_w[(size_t)rowg * CD + (col - 2)] = w[(size_t)rowg * CD + (col - 2)] + dv;
                } else if (col == 0) {
                    out_pos[rowg * 2] = pos[rowg * 2] + dv;
                } else if (col == 1) {
                    out_pos[rowg * 2 + 1] = pos[rowg * 2 + 1] + dv;
                }
            }
        }
    }
}

// ---------------------------------------------------------------------------
// conv+LN: gather-aggregate (bf16) -> swizzled LDS -> MFMA mix -> LN -> yn bf16
// ---------------------------------------------------------------------------
__global__ __launch_bounds__(256) void conv_ln_kernel(
    const ushort* __restrict__ wbf, const int* __restrict__ idx, const float* __restrict__ ker,
    const ushort* __restrict__ WcT, const float* __restrict__ bc,
    const float* __restrict__ gamma, const float* __restrict__ beta,
    ushort* __restrict__ ynb)
{
    __shared__ char aggS[64 * 256];                 // 64 rows x 128 bf16
    {
        const int p = threadIdx.x >> 2, q = threadIdx.x & 3;
        const int i = blockIdx.x * 64 + p;
        const int*   ip = idx + i * KK;
        const float* kp = ker + i * KK;
        float acc[32];
#pragma unroll
        for (int e = 0; e < 32; ++e) acc[e] = 0.f;
#pragma unroll 4
        for (int k = 0; k < KK; ++k) {
            const int j = ip[k];
            const float kv = kp[k];
            const ushort* rp = wbf + (size_t)j * CD + q * 32;
#pragma unroll
            for (int jj = 0; jj < 4; ++jj) {
                const short8v v = *(const short8v*)(rp + jj * 8);
#pragma unroll
                for (int e = 0; e < 8; ++e)
                    acc[jj * 8 + e] += kv * bf2f((ushort)v[e]);
            }
        }
#pragma unroll
        for (int jj = 0; jj < 4; ++jj) {
            short8v pack;
#pragma unroll
            for (int e = 0; e < 8; ++e) pack[e] = (short)f2bf(acc[jj * 8 + e]);
            int byte = p * 256 + q * 64 + jj * 16;
            byte ^= ((p & 7) << 4);
            *(short8v*)(aggS + byte) = pack;
        }
    }
    __syncthreads();

    const int l = threadIdx.x & 63, wave = threadIdx.x >> 6;
    const int a = l & 15, g = l >> 4;
    const int m0 = wave * 16;
    const f32x4 z4 = {0.f, 0.f, 0.f, 0.f};
    f32x4 accc[8];
#pragma unroll
    for (int nt = 0; nt < 8; ++nt) accc[nt] = z4;
#pragma unroll
    for (int ks = 0; ks < 4; ++ks) {
        const int row = m0 + a;
        int byte = row * 256 + ks * 64 + g * 16;
        byte ^= ((row & 7) << 4);
        const short8v av = *(const short8v*)(aggS + byte);
#pragma unroll
        for (int nt = 0; nt < 8; ++nt) {
            const short8v bv = *(const short8v*)(WcT + (nt * 16 + a) * CD + ks * 32 + g * 8);
            accc[nt] = __builtin_amdgcn_mfma_f32_16x16x32_bf16(av, bv, accc[nt], 0, 0, 0);
        }
    }
    float bcv[8], gv[8], btv[8];
#pragma unroll
    for (int nt = 0; nt < 8; ++nt) {
        bcv[nt] = bc[nt * 16 + a];
        gv[nt]  = gamma[nt * 16 + a];
        btv[nt] = beta[nt * 16 + a];
    }
#pragma unroll
    for (int r = 0; r < 4; ++r) {
        float s = 0.f;
#pragma unroll
        for (int nt = 0; nt < 8; ++nt) s += accc[nt][r] + bcv[nt];
        s += __shfl_xor(s, 1); s += __shfl_xor(s, 2); s += __shfl_xor(s, 4); s += __shfl_xor(s, 8);
        const float mu = s * (1.f / 128.f);
        float v = 0.f;
#pragma unroll
        for (int nt = 0; nt < 8; ++nt) { const float t = accc[nt][r] + bcv[nt] - mu; v += t * t; }
        v += __shfl_xor(v, 1); v += __shfl_xor(v, 2); v += __shfl_xor(v, 4); v += __shfl_xor(v, 8);
        const float rs = rsqrtf(v * (1.f / 128.f) + 1e-5f);
        const int rowg = blockIdx.x * 64 + m0 + 4 * g + r;
#pragma unroll
        for (int nt = 0; nt < 8; ++nt) {
            const float o = (accc[nt][r] + bcv[nt] - mu) * rs * gv[nt] + btv[nt];
            ynb[(size_t)rowg * CD + nt * 16 + a] = f2bf(o);
        }
    }
}

// ---------------------------------------------------------------------------
// sample: sampled = (sum_k ker * yn_bf16[idx]) / den
// ---------------------------------------------------------------------------
__global__ __launch_bounds__(256) void sample_kernel(
    const ushort* __restrict__ ynb, const int* __restrict__ idx, const float* __restrict__ ker,
    const float* __restrict__ den, float* __restrict__ outS)
{
    const int p = threadIdx.x >> 2, q = threadIdx.x & 3;
    const int i = blockIdx.x * 64 + p;
    const int*   ip = idx + i * KK;
    const float* kp = ker + i * KK;
    float acc[32];
#pragma unroll
    for (int e = 0; e < 32; ++e) acc[e] = 0.f;
#pragma unroll 4
    for (int k = 0; k < KK; ++k) {
        const int j = ip[k];
        const float kv = kp[k];
        const ushort* rp = ynb + (size_t)j * CD + q * 32;
#pragma unroll
        for (int jj = 0; jj < 4; ++jj) {
            const short8v v = *(const short8v*)(rp + jj * 8);
#pragma unroll
            for (int e = 0; e < 8; ++e)
                acc[jj * 8 + e] += kv * bf2f((ushort)v[e]);
        }
    }
    const float inv = 1.0f / den[i];
    float* op = outS + (size_t)i * CD + q * 32;
#pragma unroll
    for (int jj = 0; jj < 8; ++jj)
        *(float4*)(op + jj * 4) = make_float4(acc[jj*4] * inv, acc[jj*4+1] * inv,
                                              acc[jj*4+2] * inv, acc[jj*4+3] * inv);
}

extern "C" void kernel_launch(void* const* d_in, const int* in_sizes, int n_in,
                              void* d_out, int out_size, void* d_ws, size_t ws_size,
                              hipStream_t stream)
{
    (void)in_sizes; (void)n_in; (void)out_size; (void)ws_size;
    const float* pos   = (const float*)d_in[0];
    const float* wts   = (const float*)d_in[1];
    // d_in[2] = batch (sorted, equal-sized) -> implicit: scene = i / 2048
    const float* Wc    = (const float*)d_in[3];
    const float* bc    = (const float*)d_in[4];
    const float* gamma = (const float*)d_in[5];
    const float* beta  = (const float*)d_in[6];
    const float* W1    = (const float*)d_in[7];
    const float* b1    = (const float*)d_in[8];
    const float* W2    = (const float*)d_in[9];
    const float* b2    = (const float*)d_in[10];

    float* out_pos = (float*)d_out;
    float* out_w   = out_pos + NTOT * 2;
    float* out_s   = out_w + NTOT * CD;

    // workspace layout (bytes), total ~21.9 MB
    char* wsb = (char*)d_ws;
    int*    idxW    = (int*)(wsb);                               // 2 MB
    float*  kerW    = (float*)(wsb + 2097152);                   // 2 MB
    float*  denW    = (float*)(wsb + 4194304);                   // 128 KB
    ushort* ynbW    = (ushort*)(wsb + 4325376);                  // 8 MB
    ushort* wbfW    = (ushort*)(wsb + 12713984);                 // 8 MB
    ushort* WcTW    = (ushort*)(wsb + 21102592);                 // 32 KB
    ushort* W1TW    = (ushort*)(wsb + 21135360);                 // 64 KB
    ushort* W2TW    = (ushort*)(wsb + 21200896);                 // 72 KB
    float2* sposW   = (float2*)(wsb + 21274624);                 // 256 KB
    int*    soidxW  = (int*)(wsb + 21536768);                    // 128 KB
    int*    cstartW = (int*)(wsb + 21667840);                    // 66 KB
    float4* bboxW   = (float4*)(wsb + 21815360);                 // 256 B

    build_prep_kernel<<<1040, 256, 0, stream>>>(pos, sposW, soidxW, cstartW, bboxW,
                                                wts, Wc, W1, W2, wbfW, WcTW, W1TW, W2TW);
    knn_mlp_kernel<<<1536, 256, 0, stream>>>(sposW, soidxW, cstartW, bboxW, idxW, kerW, denW,
                                             wbfW, wts, pos, W1TW, b1, W2TW, b2, out_pos, out_w);
    conv_ln_kernel<<<512, 256, 0, stream>>>(wbfW, idxW, kerW, WcTW, bc, gamma, beta, ynbW);
    sample_kernel<<<512, 256, 0, stream>>>(ynbW, idxW, kerW, denW, out_s);
}

// Round 11
// 230.203 us; speedup vs baseline: 2.1964x; 2.1964x over previous
//
#include <hip/hip_runtime.h>
#include <math.h>

#define NTOT   32768
#define NSCN   16
#define NPS    2048
#define KK     16
#define CD     128
#define HD     256
#define GC     48      // grid cells per axis (center cells ~7 pts at N(0,2) density)

typedef __attribute__((ext_vector_type(8))) short short8v;   // bf16x8 MFMA frag
typedef __attribute__((ext_vector_type(4))) float f32x4;     // MFMA accumulator
typedef unsigned long long u64;

__device__ __forceinline__ ushort f2bf(float f) {            // RNE f32->bf16
    uint u = __float_as_uint(f);
    u += 0x7FFFu + ((u >> 16) & 1u);
    return (ushort)(u >> 16);
}
__device__ __forceinline__ float bf2f(ushort h) {
    return __uint_as_float(((uint)h) << 16);
}

// ---------------------------------------------------------------------------
// K1: fused grid build (blocks 0..15, counting sort per scene) + prep
// (blocks 16.., w->bf16 and transposed bf16 weights, grid-stride).
// Prefix scan: 2304 cells = 256 threads x 9 (R5-proven chunking).
// ---------------------------------------------------------------------------
__global__ __launch_bounds__(256) void build_prep_kernel(
    const float* __restrict__ pos,
    float2* __restrict__ spos, int* __restrict__ soidx,
    int* __restrict__ cstart, float4* __restrict__ bboxg,
    const float* __restrict__ w, const float* __restrict__ Wc,
    const float* __restrict__ W1, const float* __restrict__ W2,
    ushort* __restrict__ wbf, ushort* __restrict__ WcT,
    ushort* __restrict__ W1T, ushort* __restrict__ W2T)
{
    __shared__ int hist[GC * GC];
    __shared__ int scan_[GC * GC];
    __shared__ int part[256];
    __shared__ float4 wred[4];
    __shared__ float4 bbS;

    if (blockIdx.x >= 16) {
        // ---- prep path ----
        const int n_wb = NTOT * CD;
        const int n_wc = CD * CD;
        const int n_w1 = HD * CD;
        const int n_w2 = 144 * HD;
        const int total = n_wb + n_wc + n_w1 + n_w2;
        const int stride = (gridDim.x - 16) * 256;
        for (int t = (blockIdx.x - 16) * 256 + threadIdx.x; t < total; t += stride) {
            if (t < n_wb) {
                wbf[t] = f2bf(w[t]);
            } else if (t < n_wb + n_wc) {
                const int e = t - n_wb; const int n = e >> 7, k = e & 127;
                WcT[e] = f2bf(Wc[k * CD + n]);
            } else if (t < n_wb + n_wc + n_w1) {
                const int e = t - n_wb - n_wc; const int n = e >> 7, k = e & 127;
                W1T[e] = f2bf(W1[k * HD + n]);
            } else {
                const int e = t - n_wb - n_wc - n_w1; const int n = e >> 8, k = e & 255;
                W2T[e] = (n < 130) ? f2bf(W2[k * 130 + n]) : (ushort)0;
            }
        }
        return;
    }

    // ---- grid build path (one block per scene) ----
    const int s = blockIdx.x;
    const float2* gp = (const float2*)pos + s * NPS;

    float xmn = 3e38f, xmx = -3e38f, ymn = 3e38f, ymx = -3e38f;
    for (int i = threadIdx.x; i < NPS; i += 256) {
        const float2 p = gp[i];
        xmn = fminf(xmn, p.x); xmx = fmaxf(xmx, p.x);
        ymn = fminf(ymn, p.y); ymx = fmaxf(ymx, p.y);
    }
#pragma unroll
    for (int off = 1; off < 64; off <<= 1) {
        xmn = fminf(xmn, __shfl_xor(xmn, off));
        xmx = fmaxf(xmx, __shfl_xor(xmx, off));
        ymn = fminf(ymn, __shfl_xor(ymn, off));
        ymx = fmaxf(ymx, __shfl_xor(ymx, off));
    }
    if ((threadIdx.x & 63) == 0) wred[threadIdx.x >> 6] = make_float4(xmn, xmx, ymn, ymx);
    __syncthreads();
    if (threadIdx.x == 0) {
        float a = wred[0].x, bx = wred[0].y, c = wred[0].z, d = wred[0].w;
        for (int i = 1; i < 4; ++i) {
            a = fminf(a, wred[i].x); bx = fmaxf(bx, wred[i].y);
            c = fminf(c, wred[i].z); d  = fmaxf(d, wred[i].w);
        }
        const float hx = fmaxf(bx - a, 1e-6f) * (1.0f / GC);
        const float hy = fmaxf(d - c, 1e-6f) * (1.0f / GC);
        bbS = make_float4(a, c, hx, hy);
        bboxg[s] = bbS;
    }
    __syncthreads();
    const float bxm = bbS.x, bym = bbS.y;
    const float ihx = 1.0f / bbS.z, ihy = 1.0f / bbS.w;

    for (int i = threadIdx.x; i < GC * GC; i += 256) hist[i] = 0;
    __syncthreads();
    for (int i = threadIdx.x; i < NPS; i += 256) {
        const float2 p = gp[i];
        int cx = (int)((p.x - bxm) * ihx); cx = cx < 0 ? 0 : (cx > GC - 1 ? GC - 1 : cx);
        int cy = (int)((p.y - bym) * ihy); cy = cy < 0 ? 0 : (cy > GC - 1 ? GC - 1 : cy);
        atomicAdd(&hist[cy * GC + cx], 1);
    }
    __syncthreads();
    // ---- exclusive prefix (2304 = 256 threads x 9) ----
    {
        const int base = threadIdx.x * 9;
        int run = 0;
#pragma unroll
        for (int j = 0; j < 9; ++j) run += hist[base + j];
        part[threadIdx.x] = run;
        __syncthreads();
        if (threadIdx.x == 0) {
            int acc = 0;
            for (int t = 0; t < 256; ++t) { const int v = part[t]; part[t] = acc; acc += v; }
        }
        __syncthreads();
        run = part[threadIdx.x];
#pragma unroll
        for (int j = 0; j < 9; ++j) { const int h = hist[base + j]; scan_[base + j] = run; run += h; }
    }
    __syncthreads();
    for (int i = threadIdx.x; i < GC * GC; i += 256) cstart[s * (GC * GC + 1) + i] = scan_[i];
    if (threadIdx.x == 0) cstart[s * (GC * GC + 1) + GC * GC] = NPS;
    __syncthreads();
    for (int i = threadIdx.x; i < NPS; i += 256) {
        const float2 p = gp[i];
        int cx = (int)((p.x - bxm) * ihx); cx = cx < 0 ? 0 : (cx > GC - 1 ? GC - 1 : cx);
        int cy = (int)((p.y - bym) * ihy); cy = cy < 0 ? 0 : (cy > GC - 1 ? GC - 1 : cy);
        const int d = atomicAdd(&scan_[cy * GC + cx], 1);
        spos[s * NPS + d] = p;
        soidx[s * NPS + d] = i;
    }
}

// ---------------------------------------------------------------------------
// K2: fused exact-KNN (8 lanes/query, octet-cooperative) + MLP (MFMA).
// 1536 blocks interleaved 2:1 (b%3<2 -> knn, else mlp).  [R7-proven structure]
// knn: 1024 blocks x 32 queries; initial clamped 3x3 square rank-partitioned
// 8 ways (disjoint); exact count-based stop; ring expansion rows halved by
// rank, cols by y-parity (disjoint); 3-level shfl merge -> jax-stable top-16.
// ---------------------------------------------------------------------------
__global__ __launch_bounds__(256, 4) void knn_mlp_kernel(
    const float2* __restrict__ spos, const int* __restrict__ soidx,
    const int* __restrict__ cstart, const float4* __restrict__ bboxg,
    int* __restrict__ idx_out, float* __restrict__ ker_out, float* __restrict__ den_out,
    const ushort* __restrict__ wbf, const float* __restrict__ w, const float* __restrict__ pos,
    const ushort* __restrict__ W1T, const float* __restrict__ b1,
    const ushort* __restrict__ W2T, const float* __restrict__ b2,
    float* __restrict__ out_pos, float* __restrict__ out_w)
{
    __shared__ __align__(16) char smem[33800];
    const int b = blockIdx.x;
    const int m3 = b % 3;

    if (m3 < 2) {
        // =================== KNN path ===================
        const int kb = (b / 3) * 2 + m3;           // 0..1023
        float2* sp  = (float2*)smem;               // 16384 B
        int*    oix = (int*)(smem + 16384);        // 8192 B
        int*    cs  = (int*)(smem + 24576);        // (GC*GC+1)*4 = 9220 B
        const int scene = kb >> 6;                 // 64 blocks per scene
        const int sbase = scene * NPS;
        for (int i = threadIdx.x; i < NPS; i += 256) { sp[i] = spos[sbase + i]; oix[i] = soidx[sbase + i]; }
        for (int i = threadIdx.x; i < GC * GC + 1; i += 256) cs[i] = cstart[scene * (GC * GC + 1) + i];
        __syncthreads();

        const float4 bb = bboxg[scene];
        const float ihx = 1.0f / bb.z, ihy = 1.0f / bb.w;
        const int p = threadIdx.x >> 3;            // query slot 0..31
        const int r = threadIdx.x & 7;             // octet lane
        const int qi = (kb & 63) * 32 + p;         // sorted-order point index
        const float2 my = sp[qi];
        int cx = (int)((my.x - bb.x) * ihx); cx = cx < 0 ? 0 : (cx > GC - 1 ? GC - 1 : cx);
        int cy = (int)((my.y - bb.y) * ihy); cy = cy < 0 ? 0 : (cy > GC - 1 ? GC - 1 : cy);

        u64 key[16];
#pragma unroll
        for (int s_ = 0; s_ < 16; ++s_) key[s_] = ~0ULL;

#define SCANBODY(E) { \
    const float2 c2 = sp[E]; \
    const float ddx = c2.x - my.x, ddy = c2.y - my.y; \
    const float d2 = __fadd_rn(__fmul_rn(ddx, ddx), __fmul_rn(ddy, ddy)); \
    const uint d2b = __float_as_uint(d2); \
    if ((u64)d2b <= (key[15] >> 32)) { \
        u64 ck = (((u64)d2b) << 32) | (uint)oix[E]; \
        _Pragma("unroll") \
        for (int s_ = 0; s_ < 16; ++s_) { \
            const bool sm_ = ck < key[s_]; const u64 o_ = key[s_]; \
            key[s_] = sm_ ? ck : o_; ck = sm_ ? o_ : ck; } \
    } }

        // ---- initial square R=1, rank-balanced 8 ways ----
        int xl = cx - 1 < 0 ? 0 : cx - 1, xh = cx + 1 > GC - 1 ? GC - 1 : cx + 1;
        int yl = cy - 1 < 0 ? 0 : cy - 1, yh = cy + 1 > GC - 1 ? GC - 1 : cy + 1;
        {
            int c = 0;
            for (int y = yl + r; y <= yh; y += 8) c += cs[y * GC + xh + 1] - cs[y * GC + xl];
            c += __shfl_xor(c, 1); c += __shfl_xor(c, 2); c += __shfl_xor(c, 4);
            const int t0 = (r * c) >> 3, t1 = ((r + 1) * c) >> 3;
            if (t0 < t1) {
                int y = yl, acc = 0;
                int rowc = cs[y * GC + xh + 1] - cs[y * GC + xl];
                while (acc + rowc <= t0) { acc += rowc; ++y; rowc = cs[y * GC + xh + 1] - cs[y * GC + xl]; }
                int e = cs[y * GC + xl] + (t0 - acc), eend = cs[y * GC + xh + 1];
                for (int t = t0; t < t1; ++t) {
                    while (e >= eend) { ++y; e = cs[y * GC + xl]; eend = cs[y * GC + xh + 1]; }
                    SCANBODY(e); ++e;
                }
            }
        }

        // ---- expansion: exact count stop; rows halved, cols by parity ----
        int R = 1;
        while (true) {
            if (xl == 0 && yl == 0 && xh == GC - 1 && yh == GC - 1) break;
            const float px = my.x - bb.x, py = my.y - bb.y;
            float g = 3e38f;
            if (xl > 0)      g = fminf(g, px - (float)xl * bb.z);
            if (xh < GC - 1) g = fminf(g, (float)(xh + 1) * bb.z - px);
            if (yl > 0)      g = fminf(g, py - (float)yl * bb.w);
            if (yh < GC - 1) g = fminf(g, (float)(yh + 1) * bb.w - py);
            g -= 1e-4f;                             // margin >> binning fp error
            if (g > 0.f) {
                const uint ggb = __float_as_uint(g * g);
                int c16 = 0;
#pragma unroll
                for (int s_ = 0; s_ < 16; ++s_) c16 += ((uint)(key[s_] >> 32) <= ggb) ? 1 : 0;
                c16 += __shfl_xor(c16, 1); c16 += __shfl_xor(c16, 2); c16 += __shfl_xor(c16, 4);
                if (c16 >= 16) break;               // exact: >=16 true cands within g
            }
            ++R;
            const int nxl = cx - R < 0 ? 0 : cx - R, nxh = cx + R > GC - 1 ? GC - 1 : cx + R;
            const int nyl = cy - R < 0 ? 0 : cy - R, nyh = cy + R > GC - 1 ? GC - 1 : cy + R;
            if (r < 4) {                            // new top/bottom row, halved by rank
                const int y = (r < 2) ? cy - R : cy + R;
                if (y >= 0 && y <= GC - 1) {
                    const int e0 = cs[y * GC + nxl], e1 = cs[y * GC + nxh + 1];
                    const int n = e1 - e0, h = r & 1;
                    const int es = e0 + ((n * h) >> 1), ee = e0 + ((n * (h + 1)) >> 1);
                    for (int e = es; e < ee; ++e) SCANBODY(e);
                }
            } else {                                // new left/right col, y-parity split
                const int x = (r < 6) ? cx - R : cx + R;
                if (x >= 0 && x <= GC - 1) {
                    const int ylc = nyl + ((cy - R >= 0) ? 1 : 0);
                    const int yhc = nyh - ((cy + R <= GC - 1) ? 1 : 0);
                    for (int y = ylc + (r & 1); y <= yhc; y += 2) {
                        const int c0 = y * GC + x;
                        const int e1_ = cs[c0 + 1];
                        for (int e = cs[c0]; e < e1_; ++e) SCANBODY(e);
                    }
                }
            }
            xl = nxl; xh = nxh; yl = nyl; yh = nyh;
        }
#undef SCANBODY

        // ---- 3-level octet merge (disjoint lists; stage partner first) ----
#pragma unroll
        for (int lvl = 1; lvl <= 4; lvl <<= 1) {
            u64 tmp[16];
#pragma unroll
            for (int s_ = 0; s_ < 16; ++s_) {
                const uint lo = (uint)__shfl_xor((int)(uint)(key[s_] & 0xFFFFFFFFULL), lvl);
                const uint hi = (uint)__shfl_xor((int)(uint)(key[s_] >> 32), lvl);
                tmp[s_] = (((u64)hi) << 32) | lo;
            }
#pragma unroll
            for (int s_ = 0; s_ < 16; ++s_) {
                u64 ck = tmp[s_];
                if (ck < key[15]) {
#pragma unroll
                    for (int t2 = 0; t2 < 16; ++t2) {
                        const bool sm = ck < key[t2];
                        const u64 o = key[t2];
                        key[t2] = sm ? ck : o;
                        ck      = sm ? o  : ck;
                    }
                }
            }
        }

        if (r == 0) {
            const int gq = sbase + oix[qi];         // output row = ORIGINAL index
            int iv[16]; float kv[16]; float den = 0.f;
#pragma unroll
            for (int s_ = 0; s_ < 16; ++s_) {
                const float d2 = __uint_as_float((uint)(key[s_] >> 32));
                kv[s_] = expf(-2.0f * d2);
                den += kv[s_];
                iv[s_] = sbase + (int)(key[s_] & 0xFFFFFFFFULL);
            }
            int4*   ip4 = (int4*)(idx_out + gq * KK);
            float4* kp4 = (float4*)(ker_out + gq * KK);
#pragma unroll
            for (int s_ = 0; s_ < 4; ++s_) {
                ip4[s_] = make_int4(iv[4*s_], iv[4*s_+1], iv[4*s_+2], iv[4*s_+3]);
                kp4[s_] = make_float4(kv[4*s_], kv[4*s_+1], kv[4*s_+2], kv[4*s_+3]);
            }
            den_out[gq] = den;
        }
        return;
    }

    // =================== MLP path ===================
    {
        const int mb = b / 3;                      // 0..511
        char* hS = smem;                           // 64 rows x 256 bf16 = 32 KB
        const int l = threadIdx.x & 63, wave = threadIdx.x >> 6;
        const int a = l & 15, g = l >> 4;
        const int m0 = wave * 16;
        const int rbase = mb * 64;
        const f32x4 z4 = {0.f, 0.f, 0.f, 0.f};

        f32x4 acc1[16];
#pragma unroll
        for (int nt = 0; nt < 16; ++nt) acc1[nt] = z4;
#pragma unroll
        for (int ks = 0; ks < 4; ++ks) {
            const short8v av = *(const short8v*)(wbf + (size_t)(rbase + m0 + a) * CD + ks * 32 + g * 8);
#pragma unroll
            for (int nt = 0; nt < 16; ++nt) {
                const short8v bv = *(const short8v*)(W1T + (nt * 16 + a) * CD + ks * 32 + g * 8);
                acc1[nt] = __builtin_amdgcn_mfma_f32_16x16x32_bf16(av, bv, acc1[nt], 0, 0, 0);
            }
        }
#pragma unroll
        for (int nt = 0; nt < 16; ++nt) {
            const float b1v = b1[nt * 16 + a];
#pragma unroll
            for (int rr = 0; rr < 4; ++rr) {
                const float hv = fmaxf(acc1[nt][rr] + b1v, 0.f);
                const int row = m0 + 4 * g + rr;
                int byte = row * 512 + (nt * 16 + a) * 2;
                byte ^= ((row & 7) << 4);
                *(ushort*)(hS + byte) = f2bf(hv);
            }
        }
        __syncthreads();

        f32x4 acc2[9];
#pragma unroll
        for (int nt = 0; nt < 9; ++nt) acc2[nt] = z4;
#pragma unroll
        for (int ks = 0; ks < 8; ++ks) {
            const int row = m0 + a;
            int byte = row * 512 + (ks * 32 + g * 8) * 2;
            byte ^= ((row & 7) << 4);
            const short8v av = *(const short8v*)(hS + byte);
#pragma unroll
            for (int nt = 0; nt < 9; ++nt) {
                const short8v bv = *(const short8v*)(W2T + (nt * 16 + a) * HD + ks * 32 + g * 8);
                acc2[nt] = __builtin_amdgcn_mfma_f32_16x16x32_bf16(av, bv, acc2[nt], 0, 0, 0);
            }
        }
#pragma unroll
        for (int nt = 0; nt < 9; ++nt) {
            const int col = nt * 16 + a;
            const float b2v = (col < 130) ? b2[col] : 0.f;
#pragma unroll
            for (int rr = 0; rr < 4; ++rr) {
                const int rowg = rbase + m0 + 4 * g + rr;
                const float dv = acc2[nt][rr] + b2v;
                if (col >= 2 && col < 130) {
                    out_w[(size_t)rowg * CD + (col - 2)] = w[(size_t)rowg * CD + (col - 2)] + dv;
                } else if (col == 0) {
                    out_pos[rowg * 2] = pos[rowg * 2] + dv;
                } else if (col == 1) {
                    out_pos[rowg * 2 + 1] = pos[rowg * 2 + 1] + dv;
                }
            }
        }
    }
}

// ---------------------------------------------------------------------------
// conv+LN: gather-aggregate (bf16) -> swizzled LDS -> MFMA mix -> LN -> yn bf16
// ---------------------------------------------------------------------------
__global__ __launch_bounds__(256) void conv_ln_kernel(
    const ushort* __restrict__ wbf, const int* __restrict__ idx, const float* __restrict__ ker,
    const ushort* __restrict__ WcT, const float* __restrict__ bc,
    const float* __restrict__ gamma, const float* __restrict__ beta,
    ushort* __restrict__ ynb)
{
    __shared__ char aggS[64 * 256];                 // 64 rows x 128 bf16
    {
        const int p = threadIdx.x >> 2, q = threadIdx.x & 3;
        const int i = blockIdx.x * 64 + p;
        const int*   ip = idx + i * KK;
        const float* kp = ker + i * KK;
        float acc[32];
#pragma unroll
        for (int e = 0; e < 32; ++e) acc[e] = 0.f;
#pragma unroll 4
        for (int k = 0; k < KK; ++k) {
            const int j = ip[k];
            const float kv = kp[k];
            const ushort* rp = wbf + (size_t)j * CD + q * 32;
#pragma unroll
            for (int jj = 0; jj < 4; ++jj) {
                const short8v v = *(const short8v*)(rp + jj * 8);
#pragma unroll
                for (int e = 0; e < 8; ++e)
                    acc[jj * 8 + e] += kv * bf2f((ushort)v[e]);
            }
        }
#pragma unroll
        for (int jj = 0; jj < 4; ++jj) {
            short8v pack;
#pragma unroll
            for (int e = 0; e < 8; ++e) pack[e] = (short)f2bf(acc[jj * 8 + e]);
            int byte = p * 256 + q * 64 + jj * 16;
            byte ^= ((p & 7) << 4);
            *(short8v*)(aggS + byte) = pack;
        }
    }
    __syncthreads();

    const int l = threadIdx.x & 63, wave = threadIdx.x >> 6;
    const int a = l & 15, g = l >> 4;
    const int m0 = wave * 16;
    const f32x4 z4 = {0.f, 0.f, 0.f, 0.f};
    f32x4 accc[8];
#pragma unroll
    for (int nt = 0; nt < 8; ++nt) accc[nt] = z4;
#pragma unroll
    for (int ks = 0; ks < 4; ++ks) {
        const int row = m0 + a;
        int byte = row * 256 + ks * 64 + g * 16;
        byte ^= ((row & 7) << 4);
        const short8v av = *(const short8v*)(aggS + byte);
#pragma unroll
        for (int nt = 0; nt < 8; ++nt) {
            const short8v bv = *(const short8v*)(WcT + (nt * 16 + a) * CD + ks * 32 + g * 8);
            accc[nt] = __builtin_amdgcn_mfma_f32_16x16x32_bf16(av, bv, accc[nt], 0, 0, 0);
        }
    }
    float bcv[8], gv[8], btv[8];
#pragma unroll
    for (int nt = 0; nt < 8; ++nt) {
        bcv[nt] = bc[nt * 16 + a];
        gv[nt]  = gamma[nt * 16 + a];
        btv[nt] = beta[nt * 16 + a];
    }
#pragma unroll
    for (int r = 0; r < 4; ++r) {
        float s = 0.f;
#pragma unroll
        for (int nt = 0; nt < 8; ++nt) s += accc[nt][r] + bcv[nt];
        s += __shfl_xor(s, 1); s += __shfl_xor(s, 2); s += __shfl_xor(s, 4); s += __shfl_xor(s, 8);
        const float mu = s * (1.f / 128.f);
        float v = 0.f;
#pragma unroll
        for (int nt = 0; nt < 8; ++nt) { const float t = accc[nt][r] + bcv[nt] - mu; v += t * t; }
        v += __shfl_xor(v, 1); v += __shfl_xor(v, 2); v += __shfl_xor(v, 4); v += __shfl_xor(v, 8);
        const float rs = rsqrtf(v * (1.f / 128.f) + 1e-5f);
        const int rowg = blockIdx.x * 64 + m0 + 4 * g + r;
#pragma unroll
        for (int nt = 0; nt < 8; ++nt) {
            const float o = (accc[nt][r] + bcv[nt] - mu) * rs * gv[nt] + btv[nt];
            ynb[(size_t)rowg * CD + nt * 16 + a] = f2bf(o);
        }
    }
}

// ---------------------------------------------------------------------------
// sample: sampled = (sum_k ker * yn_bf16[idx]) / den
// ---------------------------------------------------------------------------
__global__ __launch_bounds__(256) void sample_kernel(
    const ushort* __restrict__ ynb, const int* __restrict__ idx, const float* __restrict__ ker,
    const float* __restrict__ den, float* __restrict__ outS)
{
    const int p = threadIdx.x >> 2, q = threadIdx.x & 3;
    const int i = blockIdx.x * 64 + p;
    const int*   ip = idx + i * KK;
    const float* kp = ker + i * KK;
    float acc[32];
#pragma unroll
    for (int e = 0; e < 32; ++e) acc[e] = 0.f;
#pragma unroll 4
    for (int k = 0; k < KK; ++k) {
        const int j = ip[k];
        const float kv = kp[k];
        const ushort* rp = ynb + (size_t)j * CD + q * 32;
#pragma unroll
        for (int jj = 0; jj < 4; ++jj) {
            const short8v v = *(const short8v*)(rp + jj * 8);
#pragma unroll
            for (int e = 0; e < 8; ++e)
                acc[jj * 8 + e] += kv * bf2f((ushort)v[e]);
        }
    }
    const float inv = 1.0f / den[i];
    float* op = outS + (size_t)i * CD + q * 32;
#pragma unroll
    for (int jj = 0; jj < 8; ++jj)
        *(float4*)(op + jj * 4) = make_float4(acc[jj*4] * inv, acc[jj*4+1] * inv,
                                              acc[jj*4+2] * inv, acc[jj*4+3] * inv);
}

extern "C" void kernel_launch(void* const* d_in, const int* in_sizes, int n_in,
                              void* d_out, int out_size, void* d_ws, size_t ws_size,
                              hipStream_t stream)
{
    (void)in_sizes; (void)n_in; (void)out_size; (void)ws_size;
    const float* pos   = (const float*)d_in[0];
    const float* wts   = (const float*)d_in[1];
    // d_in[2] = batch (sorted, equal-sized) -> implicit: scene = i / 2048
    const float* Wc    = (const float*)d_in[3];
    const float* bc    = (const float*)d_in[4];
    const float* gamma = (const float*)d_in[5];
    const float* beta  = (const float*)d_in[6];
    const float* W1    = (const float*)d_in[7];
    const float* b1    = (const float*)d_in[8];
    const float* W2    = (const float*)d_in[9];
    const float* b2    = (const float*)d_in[10];

    float* out_pos = (float*)d_out;
    float* out_w   = out_pos + NTOT * 2;
    float* out_s   = out_w + NTOT * CD;

    // workspace layout (bytes), total ~21.9 MB
    char* wsb = (char*)d_ws;
    int*    idxW    = (int*)(wsb);                               // 2 MB
    float*  kerW    = (float*)(wsb + 2097152);                   // 2 MB
    float*  denW    = (float*)(wsb + 4194304);                   // 128 KB
    ushort* ynbW    = (ushort*)(wsb + 4325376);                  // 8 MB
    ushort* wbfW    = (ushort*)(wsb + 12713984);                 // 8 MB
    ushort* WcTW    = (ushort*)(wsb + 21102592);                 // 32 KB
    ushort* W1TW    = (ushort*)(wsb + 21135360);                 // 64 KB
    ushort* W2TW    = (ushort*)(wsb + 21200896);                 // 72 KB
    float2* sposW   = (float2*)(wsb + 21274624);                 // 256 KB
    int*    soidxW  = (int*)(wsb + 21536768);                    // 128 KB
    int*    cstartW = (int*)(wsb + 21667840);                    // (48*48+1)*16*4 = 147520 B
    float4* bboxW   = (float4*)(wsb + 21815360);                 // 256 B

    build_prep_kernel<<<1040, 256, 0, stream>>>(pos, sposW, soidxW, cstartW, bboxW,
                                                wts, Wc, W1, W2, wbfW, WcTW, W1TW, W2TW);
    knn_mlp_kernel<<<1536, 256, 0, stream>>>(sposW, soidxW, cstartW, bboxW, idxW, kerW, denW,
                                             wbfW, wts, pos, W1TW, b1, W2TW, b2, out_pos, out_w);
    conv_ln_kernel<<<512, 256, 0, stream>>>(wbfW, idxW, kerW, WcTW, bc, gamma, beta, ynbW);
    sample_kernel<<<512, 256, 0, stream>>>(ynbW, idxW, kerW, denW, out_s);
}

// Round 12
// 195.836 us; speedup vs baseline: 2.5818x; 1.1755x over previous
//
#include <hip/hip_runtime.h>
#include <math.h>

#define NTOT   32768
#define NSCN   16
#define NPS    2048
#define KK     16
#define CD     128
#define HD     256
#define GC     48      // grid cells per axis

typedef __attribute__((ext_vector_type(8))) short short8v;   // bf16x8 MFMA frag
typedef __attribute__((ext_vector_type(4))) float f32x4;     // MFMA accumulator
typedef unsigned long long u64;

__device__ __forceinline__ ushort f2bf(float f) {            // RNE f32->bf16
    uint u = __float_as_uint(f);
    u += 0x7FFFu + ((u >> 16) & 1u);
    return (ushort)(u >> 16);
}
__device__ __forceinline__ float bf2f(ushort h) {
    return __uint_as_float(((uint)h) << 16);
}

// ---------------------------------------------------------------------------
// K1: fused grid build (blocks 0..15, counting sort per scene) + prep
// (blocks 16.., w->bf16 and transposed bf16 weights, grid-stride).
// ---------------------------------------------------------------------------
__global__ __launch_bounds__(256) void build_prep_kernel(
    const float* __restrict__ pos,
    float2* __restrict__ spos, int* __restrict__ soidx,
    int* __restrict__ cstart, float4* __restrict__ bboxg,
    const float* __restrict__ w, const float* __restrict__ Wc,
    const float* __restrict__ W1, const float* __restrict__ W2,
    ushort* __restrict__ wbf, ushort* __restrict__ WcT,
    ushort* __restrict__ W1T, ushort* __restrict__ W2T)
{
    __shared__ int hist[GC * GC];
    __shared__ int scan_[GC * GC];
    __shared__ int part[256];
    __shared__ float4 wred[4];
    __shared__ float4 bbS;

    if (blockIdx.x >= 16) {
        // ---- prep path ----
        const int n_wb = NTOT * CD;
        const int n_wc = CD * CD;
        const int n_w1 = HD * CD;
        const int n_w2 = 144 * HD;
        const int total = n_wb + n_wc + n_w1 + n_w2;
        const int stride = (gridDim.x - 16) * 256;
        for (int t = (blockIdx.x - 16) * 256 + threadIdx.x; t < total; t += stride) {
            if (t < n_wb) {
                wbf[t] = f2bf(w[t]);
            } else if (t < n_wb + n_wc) {
                const int e = t - n_wb; const int n = e >> 7, k = e & 127;
                WcT[e] = f2bf(Wc[k * CD + n]);
            } else if (t < n_wb + n_wc + n_w1) {
                const int e = t - n_wb - n_wc; const int n = e >> 7, k = e & 127;
                W1T[e] = f2bf(W1[k * HD + n]);
            } else {
                const int e = t - n_wb - n_wc - n_w1; const int n = e >> 8, k = e & 255;
                W2T[e] = (n < 130) ? f2bf(W2[k * 130 + n]) : (ushort)0;
            }
        }
        return;
    }

    // ---- grid build path (one block per scene) ----
    const int s = blockIdx.x;
    const float2* gp = (const float2*)pos + s * NPS;

    float xmn = 3e38f, xmx = -3e38f, ymn = 3e38f, ymx = -3e38f;
    for (int i = threadIdx.x; i < NPS; i += 256) {
        const float2 p = gp[i];
        xmn = fminf(xmn, p.x); xmx = fmaxf(xmx, p.x);
        ymn = fminf(ymn, p.y); ymx = fmaxf(ymx, p.y);
    }
#pragma unroll
    for (int off = 1; off < 64; off <<= 1) {
        xmn = fminf(xmn, __shfl_xor(xmn, off));
        xmx = fmaxf(xmx, __shfl_xor(xmx, off));
        ymn = fminf(ymn, __shfl_xor(ymn, off));
        ymx = fmaxf(ymx, __shfl_xor(ymx, off));
    }
    if ((threadIdx.x & 63) == 0) wred[threadIdx.x >> 6] = make_float4(xmn, xmx, ymn, ymx);
    __syncthreads();
    if (threadIdx.x == 0) {
        float a = wred[0].x, bx = wred[0].y, c = wred[0].z, d = wred[0].w;
        for (int i = 1; i < 4; ++i) {
            a = fminf(a, wred[i].x); bx = fmaxf(bx, wred[i].y);
            c = fminf(c, wred[i].z); d  = fmaxf(d, wred[i].w);
        }
        const float hx = fmaxf(bx - a, 1e-6f) * (1.0f / GC);
        const float hy = fmaxf(d - c, 1e-6f) * (1.0f / GC);
        bbS = make_float4(a, c, hx, hy);
        bboxg[s] = bbS;
    }
    __syncthreads();
    const float bxm = bbS.x, bym = bbS.y;
    const float ihx = 1.0f / bbS.z, ihy = 1.0f / bbS.w;

    for (int i = threadIdx.x; i < GC * GC; i += 256) hist[i] = 0;
    __syncthreads();
    for (int i = threadIdx.x; i < NPS; i += 256) {
        const float2 p = gp[i];
        int cx = (int)((p.x - bxm) * ihx); cx = cx < 0 ? 0 : (cx > GC - 1 ? GC - 1 : cx);
        int cy = (int)((p.y - bym) * ihy); cy = cy < 0 ? 0 : (cy > GC - 1 ? GC - 1 : cy);
        atomicAdd(&hist[cy * GC + cx], 1);
    }
    __syncthreads();
    // ---- exclusive prefix (2304 = 256 threads x 9) ----
    {
        const int base = threadIdx.x * 9;
        int run = 0;
#pragma unroll
        for (int j = 0; j < 9; ++j) run += hist[base + j];
        part[threadIdx.x] = run;
        __syncthreads();
        if (threadIdx.x == 0) {
            int acc = 0;
            for (int t = 0; t < 256; ++t) { const int v = part[t]; part[t] = acc; acc += v; }
        }
        __syncthreads();
        run = part[threadIdx.x];
#pragma unroll
        for (int j = 0; j < 9; ++j) { const int h = hist[base + j]; scan_[base + j] = run; run += h; }
    }
    __syncthreads();
    for (int i = threadIdx.x; i < GC * GC; i += 256) cstart[s * (GC * GC + 1) + i] = scan_[i];
    if (threadIdx.x == 0) cstart[s * (GC * GC + 1) + GC * GC] = NPS;
    __syncthreads();
    for (int i = threadIdx.x; i < NPS; i += 256) {
        const float2 p = gp[i];
        int cx = (int)((p.x - bxm) * ihx); cx = cx < 0 ? 0 : (cx > GC - 1 ? GC - 1 : cx);
        int cy = (int)((p.y - bym) * ihy); cy = cy < 0 ? 0 : (cy > GC - 1 ? GC - 1 : cy);
        const int d = atomicAdd(&scan_[cy * GC + cx], 1);
        spos[s * NPS + d] = p;
        soidx[s * NPS + d] = i;
    }
}

// ---------------------------------------------------------------------------
// K2: fused exact-KNN + MLP (MFMA), 2:1 interleave. [R10 skeleton]
// KNN: value-only u32 top-16 scan (cheap min/max chain) + exact count stop;
// bitonic octet value-merge -> T = exact joint 16th d2; recovery re-scan of
// the final square gated by d2<=T feeds the PROVEN u64 (d2,idx) insert +
// 3-level octet merge -> exact jax-stable top-16 (bit-identical outputs).
// ---------------------------------------------------------------------------
__global__ __launch_bounds__(256, 4) void knn_mlp_kernel(
    const float2* __restrict__ spos, const int* __restrict__ soidx,
    const int* __restrict__ cstart, const float4* __restrict__ bboxg,
    int* __restrict__ idx_out, float* __restrict__ ker_out, float* __restrict__ den_out,
    const ushort* __restrict__ wbf, const float* __restrict__ w, const float* __restrict__ pos,
    const ushort* __restrict__ W1T, const float* __restrict__ b1,
    const ushort* __restrict__ W2T, const float* __restrict__ b2,
    float* __restrict__ out_pos, float* __restrict__ out_w)
{
    __shared__ __align__(16) char smem[33800];
    const int b = blockIdx.x;
    const int m3 = b % 3;

    if (m3 < 2) {
        // =================== KNN path ===================
        const int kb = (b / 3) * 2 + m3;           // 0..1023
        float2* sp  = (float2*)smem;               // 16384 B
        int*    oix = (int*)(smem + 16384);        // 8192 B
        int*    cs  = (int*)(smem + 24576);        // (GC*GC+1)*4 = 9220 B
        const int scene = kb >> 6;                 // 64 blocks per scene
        const int sbase = scene * NPS;
        for (int i = threadIdx.x; i < NPS; i += 256) { sp[i] = spos[sbase + i]; oix[i] = soidx[sbase + i]; }
        for (int i = threadIdx.x; i < GC * GC + 1; i += 256) cs[i] = cstart[scene * (GC * GC + 1) + i];
        __syncthreads();

        const float4 bb = bboxg[scene];
        const float ihx = 1.0f / bb.z, ihy = 1.0f / bb.w;
        const int p = threadIdx.x >> 3;            // query slot 0..31
        const int r = threadIdx.x & 7;             // octet lane
        const int qi = (kb & 63) * 32 + p;         // sorted-order point index
        const float2 my = sp[qi];
        int cx = (int)((my.x - bb.x) * ihx); cx = cx < 0 ? 0 : (cx > GC - 1 ? GC - 1 : cx);
        int cy = (int)((my.y - bb.y) * ihy); cy = cy < 0 ? 0 : (cy > GC - 1 ? GC - 1 : cy);

        uint key[16];
#pragma unroll
        for (int s_ = 0; s_ < 16; ++s_) key[s_] = 0xFFFFFFFFu;

        // value-only scan body: sorted-16 min/max chain (no index tracking)
#define SCANV(E) { \
    const float2 c2 = sp[E]; \
    const float ddx = c2.x - my.x, ddy = c2.y - my.y; \
    const float d2 = __fadd_rn(__fmul_rn(ddx, ddx), __fmul_rn(ddy, ddy)); \
    uint v_ = __float_as_uint(d2); \
    if (v_ < key[15]) { \
        _Pragma("unroll") \
        for (int s_ = 0; s_ < 16; ++s_) { \
            const uint lo_ = min(key[s_], v_); v_ = max(key[s_], v_); key[s_] = lo_; } \
    } }

        // ---- initial square R=1, rank-balanced 8 ways ----
        int xl = cx - 1 < 0 ? 0 : cx - 1, xh = cx + 1 > GC - 1 ? GC - 1 : cx + 1;
        int yl = cy - 1 < 0 ? 0 : cy - 1, yh = cy + 1 > GC - 1 ? GC - 1 : cy + 1;
        {
            int c = 0;
            for (int y = yl + r; y <= yh; y += 8) c += cs[y * GC + xh + 1] - cs[y * GC + xl];
            c += __shfl_xor(c, 1); c += __shfl_xor(c, 2); c += __shfl_xor(c, 4);
            const int t0 = (r * c) >> 3, t1 = ((r + 1) * c) >> 3;
            if (t0 < t1) {
                int y = yl, acc = 0;
                int rowc = cs[y * GC + xh + 1] - cs[y * GC + xl];
                while (acc + rowc <= t0) { acc += rowc; ++y; rowc = cs[y * GC + xh + 1] - cs[y * GC + xl]; }
                int e = cs[y * GC + xl] + (t0 - acc), eend = cs[y * GC + xh + 1];
                for (int t = t0; t < t1; ++t) {
                    while (e >= eend) { ++y; e = cs[y * GC + xl]; eend = cs[y * GC + xh + 1]; }
                    SCANV(e); ++e;
                }
            }
        }

        // ---- expansion: exact count stop; rows halved, cols by parity ----
        int R = 1;
        while (true) {
            if (xl == 0 && yl == 0 && xh == GC - 1 && yh == GC - 1) break;
            const float px = my.x - bb.x, py = my.y - bb.y;
            float g = 3e38f;
            if (xl > 0)      g = fminf(g, px - (float)xl * bb.z);
            if (xh < GC - 1) g = fminf(g, (float)(xh + 1) * bb.z - px);
            if (yl > 0)      g = fminf(g, py - (float)yl * bb.w);
            if (yh < GC - 1) g = fminf(g, (float)(yh + 1) * bb.w - py);
            g -= 1e-4f;                             // margin >> binning fp error
            if (g > 0.f) {
                const uint ggb = __float_as_uint(g * g);
                int c16 = 0;
#pragma unroll
                for (int s_ = 0; s_ < 16; ++s_) c16 += (key[s_] <= ggb) ? 1 : 0;
                c16 += __shfl_xor(c16, 1); c16 += __shfl_xor(c16, 2); c16 += __shfl_xor(c16, 4);
                if (c16 >= 16) break;               // exact: >=16 true cands within g
            }
            ++R;
            const int nxl = cx - R < 0 ? 0 : cx - R, nxh = cx + R > GC - 1 ? GC - 1 : cx + R;
            const int nyl = cy - R < 0 ? 0 : cy - R, nyh = cy + R > GC - 1 ? GC - 1 : cy + R;
            if (r < 4) {                            // new top/bottom row, halved by rank
                const int y = (r < 2) ? cy - R : cy + R;
                if (y >= 0 && y <= GC - 1) {
                    const int e0 = cs[y * GC + nxl], e1 = cs[y * GC + nxh + 1];
                    const int n = e1 - e0, h = r & 1;
                    const int es = e0 + ((n * h) >> 1), ee = e0 + ((n * (h + 1)) >> 1);
                    for (int e = es; e < ee; ++e) SCANV(e);
                }
            } else {                                // new left/right col, y-parity split
                const int x = (r < 6) ? cx - R : cx + R;
                if (x >= 0 && x <= GC - 1) {
                    const int ylc = nyl + ((cy - R >= 0) ? 1 : 0);
                    const int yhc = nyh - ((cy + R <= GC - 1) ? 1 : 0);
                    for (int y = ylc + (r & 1); y <= yhc; y += 2) {
                        const int c0 = y * GC + x;
                        const int e1_ = cs[c0 + 1];
                        for (int e = cs[c0]; e < e1_; ++e) SCANV(e);
                    }
                }
            }
            xl = nxl; xh = nxh; yl = nyl; yh = nyh;
        }
#undef SCANV

        // ---- bitonic octet value-merge: joint sorted 16 smallest d2 ----
#pragma unroll
        for (int lvl = 1; lvl <= 4; lvl <<= 1) {
            uint bv[16];
#pragma unroll
            for (int s_ = 0; s_ < 16; ++s_) bv[s_] = (uint)__shfl_xor((int)key[s_], lvl);
            uint t[16];
#pragma unroll
            for (int i = 0; i < 16; ++i) t[i] = min(key[i], bv[15 - i]);   // lower half
#pragma unroll
            for (int d = 8; d >= 1; d >>= 1) {                             // bitonic clean
#pragma unroll
                for (int i = 0; i < 16; ++i) {
                    if ((i & d) == 0) {
                        const uint lo = min(t[i], t[i + d]);
                        t[i + d] = max(t[i], t[i + d]);
                        t[i] = lo;
                    }
                }
            }
#pragma unroll
            for (int s_ = 0; s_ < 16; ++s_) key[s_] = t[s_];
        }
        const uint T = key[15];                     // exact joint 16th distance

        // ---- recovery re-scan of final square: d2<=T -> u64 (d2,idx) insert ----
        u64 k64[16];
#pragma unroll
        for (int s_ = 0; s_ < 16; ++s_) k64[s_] = ~0ULL;
        {
            int c = 0;
            for (int y = yl + r; y <= yh; y += 8) c += cs[y * GC + xh + 1] - cs[y * GC + xl];
            c += __shfl_xor(c, 1); c += __shfl_xor(c, 2); c += __shfl_xor(c, 4);
            const int t0 = (r * c) >> 3, t1 = ((r + 1) * c) >> 3;
            if (t0 < t1) {
                int y = yl, acc = 0;
                int rowc = cs[y * GC + xh + 1] - cs[y * GC + xl];
                while (acc + rowc <= t0) { acc += rowc; ++y; rowc = cs[y * GC + xh + 1] - cs[y * GC + xl]; }
                int e = cs[y * GC + xl] + (t0 - acc), eend = cs[y * GC + xh + 1];
                for (int t = t0; t < t1; ++t) {
                    while (e >= eend) { ++y; e = cs[y * GC + xl]; eend = cs[y * GC + xh + 1]; }
                    const float2 c2 = sp[e];
                    const float ddx = c2.x - my.x, ddy = c2.y - my.y;
                    const float d2 = __fadd_rn(__fmul_rn(ddx, ddx), __fmul_rn(ddy, ddy));
                    const uint d2b = __float_as_uint(d2);
                    if (d2b <= T) {                 // superset of true top-16
                        u64 ck = (((u64)d2b) << 32) | (uint)oix[e];
                        if (ck < k64[15]) {
#pragma unroll
                            for (int s_ = 0; s_ < 16; ++s_) {
                                const bool sm_ = ck < k64[s_]; const u64 o_ = k64[s_];
                                k64[s_] = sm_ ? ck : o_; ck = sm_ ? o_ : ck;
                            }
                        }
                    }
                    ++e;
                }
            }
        }

        // ---- 3-level octet u64 merge (sparse lists; dummies skip) ----
#pragma unroll
        for (int lvl = 1; lvl <= 4; lvl <<= 1) {
            u64 tmp[16];
#pragma unroll
            for (int s_ = 0; s_ < 16; ++s_) {
                const uint lo = (uint)__shfl_xor((int)(uint)(k64[s_] & 0xFFFFFFFFULL), lvl);
                const uint hi = (uint)__shfl_xor((int)(uint)(k64[s_] >> 32), lvl);
                tmp[s_] = (((u64)hi) << 32) | lo;
            }
#pragma unroll
            for (int s_ = 0; s_ < 16; ++s_) {
                u64 ck = tmp[s_];
                if (ck < k64[15]) {
#pragma unroll
                    for (int t2 = 0; t2 < 16; ++t2) {
                        const bool sm = ck < k64[t2];
                        const u64 o = k64[t2];
                        k64[t2] = sm ? ck : o;
                        ck      = sm ? o  : ck;
                    }
                }
            }
        }

        if (r == 0) {
            const int gq = sbase + oix[qi];         // output row = ORIGINAL index
            int iv[16]; float kv[16]; float den = 0.f;
#pragma unroll
            for (int s_ = 0; s_ < 16; ++s_) {
                const float d2 = __uint_as_float((uint)(k64[s_] >> 32));
                kv[s_] = expf(-2.0f * d2);
                den += kv[s_];
                iv[s_] = sbase + (int)(k64[s_] & 0xFFFFFFFFULL);
            }
            int4*   ip4 = (int4*)(idx_out + gq * KK);
            float4* kp4 = (float4*)(ker_out + gq * KK);
#pragma unroll
            for (int s_ = 0; s_ < 4; ++s_) {
                ip4[s_] = make_int4(iv[4*s_], iv[4*s_+1], iv[4*s_+2], iv[4*s_+3]);
                kp4[s_] = make_float4(kv[4*s_], kv[4*s_+1], kv[4*s_+2], kv[4*s_+3]);
            }
            den_out[gq] = den;
        }
        return;
    }

    // =================== MLP path ===================
    {
        const int mb = b / 3;                      // 0..511
        char* hS = smem;                           // 64 rows x 256 bf16 = 32 KB
        const int l = threadIdx.x & 63, wave = threadIdx.x >> 6;
        const int a = l & 15, g = l >> 4;
        const int m0 = wave * 16;
        const int rbase = mb * 64;
        const f32x4 z4 = {0.f, 0.f, 0.f, 0.f};

        f32x4 acc1[16];
#pragma unroll
        for (int nt = 0; nt < 16; ++nt) acc1[nt] = z4;
#pragma unroll
        for (int ks = 0; ks < 4; ++ks) {
            const short8v av = *(const short8v*)(wbf + (size_t)(rbase + m0 + a) * CD + ks * 32 + g * 8);
#pragma unroll
            for (int nt = 0; nt < 16; ++nt) {
                const short8v bv = *(const short8v*)(W1T + (nt * 16 + a) * CD + ks * 32 + g * 8);
                acc1[nt] = __builtin_amdgcn_mfma_f32_16x16x32_bf16(av, bv, acc1[nt], 0, 0, 0);
            }
        }
#pragma unroll
        for (int nt = 0; nt < 16; ++nt) {
            const float b1v = b1[nt * 16 + a];
#pragma unroll
            for (int rr = 0; rr < 4; ++rr) {
                const float hv = fmaxf(acc1[nt][rr] + b1v, 0.f);
                const int row = m0 + 4 * g + rr;
                int byte = row * 512 + (nt * 16 + a) * 2;
                byte ^= ((row & 7) << 4);
                *(ushort*)(hS + byte) = f2bf(hv);
            }
        }
        __syncthreads();

        f32x4 acc2[9];
#pragma unroll
        for (int nt = 0; nt < 9; ++nt) acc2[nt] = z4;
#pragma unroll
        for (int ks = 0; ks < 8; ++ks) {
            const int row = m0 + a;
            int byte = row * 512 + (ks * 32 + g * 8) * 2;
            byte ^= ((row & 7) << 4);
            const short8v av = *(const short8v*)(hS + byte);
#pragma unroll
            for (int nt = 0; nt < 9; ++nt) {
                const short8v bv = *(const short8v*)(W2T + (nt * 16 + a) * HD + ks * 32 + g * 8);
                acc2[nt] = __builtin_amdgcn_mfma_f32_16x16x32_bf16(av, bv, acc2[nt], 0, 0, 0);
            }
        }
#pragma unroll
        for (int nt = 0; nt < 9; ++nt) {
            const int col = nt * 16 + a;
            const float b2v = (col < 130) ? b2[col] : 0.f;
#pragma unroll
            for (int rr = 0; rr < 4; ++rr) {
                const int rowg = rbase + m0 + 4 * g + rr;
                const float dv = acc2[nt][rr] + b2v;
                if (col >= 2 && col < 130) {
                    out_w[(size_t)rowg * CD + (col - 2)] = w[(size_t)rowg * CD + (col - 2)] + dv;
                } else if (col == 0) {
                    out_pos[rowg * 2] = pos[rowg * 2] + dv;
                } else if (col == 1) {
                    out_pos[rowg * 2 + 1] = pos[rowg * 2 + 1] + dv;
                }
            }
        }
    }
}

// ---------------------------------------------------------------------------
// conv+LN: gather-aggregate (bf16) -> swizzled LDS -> MFMA mix -> LN -> yn bf16
// ---------------------------------------------------------------------------
__global__ __launch_bounds__(256) void conv_ln_kernel(
    const ushort* __restrict__ wbf, const int* __restrict__ idx, const float* __restrict__ ker,
    const ushort* __restrict__ WcT, const float* __restrict__ bc,
    const float* __restrict__ gamma, const float* __restrict__ beta,
    ushort* __restrict__ ynb)
{
    __shared__ char aggS[64 * 256];                 // 64 rows x 128 bf16
    {
        const int p = threadIdx.x >> 2, q = threadIdx.x & 3;
        const int i = blockIdx.x * 64 + p;
        const int*   ip = idx + i * KK;
        const float* kp = ker + i * KK;
        float acc[32];
#pragma unroll
        for (int e = 0; e < 32; ++e) acc[e] = 0.f;
#pragma unroll 4
        for (int k = 0; k < KK; ++k) {
            const int j = ip[k];
            const float kv = kp[k];
            const ushort* rp = wbf + (size_t)j * CD + q * 32;
#pragma unroll
            for (int jj = 0; jj < 4; ++jj) {
                const short8v v = *(const short8v*)(rp + jj * 8);
#pragma unroll
                for (int e = 0; e < 8; ++e)
                    acc[jj * 8 + e] += kv * bf2f((ushort)v[e]);
            }
        }
#pragma unroll
        for (int jj = 0; jj < 4; ++jj) {
            short8v pack;
#pragma unroll
            for (int e = 0; e < 8; ++e) pack[e] = (short)f2bf(acc[jj * 8 + e]);
            int byte = p * 256 + q * 64 + jj * 16;
            byte ^= ((p & 7) << 4);
            *(short8v*)(aggS + byte) = pack;
        }
    }
    __syncthreads();

    const int l = threadIdx.x & 63, wave = threadIdx.x >> 6;
    const int a = l & 15, g = l >> 4;
    const int m0 = wave * 16;
    const f32x4 z4 = {0.f, 0.f, 0.f, 0.f};
    f32x4 accc[8];
#pragma unroll
    for (int nt = 0; nt < 8; ++nt) accc[nt] = z4;
#pragma unroll
    for (int ks = 0; ks < 4; ++ks) {
        const int row = m0 + a;
        int byte = row * 256 + ks * 64 + g * 16;
        byte ^= ((row & 7) << 4);
        const short8v av = *(const short8v*)(aggS + byte);
#pragma unroll
        for (int nt = 0; nt < 8; ++nt) {
            const short8v bv = *(const short8v*)(WcT + (nt * 16 + a) * CD + ks * 32 + g * 8);
            accc[nt] = __builtin_amdgcn_mfma_f32_16x16x32_bf16(av, bv, accc[nt], 0, 0, 0);
        }
    }
    float bcv[8], gv[8], btv[8];
#pragma unroll
    for (int nt = 0; nt < 8; ++nt) {
        bcv[nt] = bc[nt * 16 + a];
        gv[nt]  = gamma[nt * 16 + a];
        btv[nt] = beta[nt * 16 + a];
    }
#pragma unroll
    for (int r = 0; r < 4; ++r) {
        float s = 0.f;
#pragma unroll
        for (int nt = 0; nt < 8; ++nt) s += accc[nt][r] + bcv[nt];
        s += __shfl_xor(s, 1); s += __shfl_xor(s, 2); s += __shfl_xor(s, 4); s += __shfl_xor(s, 8);
        const float mu = s * (1.f / 128.f);
        float v = 0.f;
#pragma unroll
        for (int nt = 0; nt < 8; ++nt) { const float t = accc[nt][r] + bcv[nt] - mu; v += t * t; }
        v += __shfl_xor(v, 1); v += __shfl_xor(v, 2); v += __shfl_xor(v, 4); v += __shfl_xor(v, 8);
        const float rs = rsqrtf(v * (1.f / 128.f) + 1e-5f);
        const int rowg = blockIdx.x * 64 + m0 + 4 * g + r;
#pragma unroll
        for (int nt = 0; nt < 8; ++nt) {
            const float o = (accc[nt][r] + bcv[nt] - mu) * rs * gv[nt] + btv[nt];
            ynb[(size_t)rowg * CD + nt * 16 + a] = f2bf(o);
        }
    }
}

// ---------------------------------------------------------------------------
// sample: sampled = (sum_k ker * yn_bf16[idx]) / den
// ---------------------------------------------------------------------------
__global__ __launch_bounds__(256) void sample_kernel(
    const ushort* __restrict__ ynb, const int* __restrict__ idx, const float* __restrict__ ker,
    const float* __restrict__ den, float* __restrict__ outS)
{
    const int p = threadIdx.x >> 2, q = threadIdx.x & 3;
    const int i = blockIdx.x * 64 + p;
    const int*   ip = idx + i * KK;
    const float* kp = ker + i * KK;
    float acc[32];
#pragma unroll
    for (int e = 0; e < 32; ++e) acc[e] = 0.f;
#pragma unroll 4
    for (int k = 0; k < KK; ++k) {
        const int j = ip[k];
        const float kv = kp[k];
        const ushort* rp = ynb + (size_t)j * CD + q * 32;
#pragma unroll
        for (int jj = 0; jj < 4; ++jj) {
            const short8v v = *(const short8v*)(rp + jj * 8);
#pragma unroll
            for (int e = 0; e < 8; ++e)
                acc[jj * 8 + e] += kv * bf2f((ushort)v[e]);
        }
    }
    const float inv = 1.0f / den[i];
    float* op = outS + (size_t)i * CD + q * 32;
#pragma unroll
    for (int jj = 0; jj < 8; ++jj)
        *(float4*)(op + jj * 4) = make_float4(acc[jj*4] * inv, acc[jj*4+1] * inv,
                                              acc[jj*4+2] * inv, acc[jj*4+3] * inv);
}

extern "C" void kernel_launch(void* const* d_in, const int* in_sizes, int n_in,
                              void* d_out, int out_size, void* d_ws, size_t ws_size,
                              hipStream_t stream)
{
    (void)in_sizes; (void)n_in; (void)out_size; (void)ws_size;
    const float* pos   = (const float*)d_in[0];
    const float* wts   = (const float*)d_in[1];
    // d_in[2] = batch (sorted, equal-sized) -> implicit: scene = i / 2048
    const float* Wc    = (const float*)d_in[3];
    const float* bc    = (const float*)d_in[4];
    const float* gamma = (const float*)d_in[5];
    const float* beta  = (const float*)d_in[6];
    const float* W1    = (const float*)d_in[7];
    const float* b1    = (const float*)d_in[8];
    const float* W2    = (const float*)d_in[9];
    const float* b2    = (const float*)d_in[10];

    float* out_pos = (float*)d_out;
    float* out_w   = out_pos + NTOT * 2;
    float* out_s   = out_w + NTOT * CD;

    // workspace layout (bytes), total ~21.9 MB
    char* wsb = (char*)d_ws;
    int*    idxW    = (int*)(wsb);                               // 2 MB
    float*  kerW    = (float*)(wsb + 2097152);                   // 2 MB
    float*  denW    = (float*)(wsb + 4194304);                   // 128 KB
    ushort* ynbW    = (ushort*)(wsb + 4325376);                  // 8 MB
    ushort* wbfW    = (ushort*)(wsb + 12713984);                 // 8 MB
    ushort* WcTW    = (ushort*)(wsb + 21102592);                 // 32 KB
    ushort* W1TW    = (ushort*)(wsb + 21135360);                 // 64 KB
    ushort* W2TW    = (ushort*)(wsb + 21200896);                 // 72 KB
    float2* sposW   = (float2*)(wsb + 21274624);                 // 256 KB
    int*    soidxW  = (int*)(wsb + 21536768);                    // 128 KB
    int*    cstartW = (int*)(wsb + 21667840);                    // (48*48+1)*16*4 B
    float4* bboxW   = (float4*)(wsb + 21815360);                 // 256 B

    build_prep_kernel<<<1040, 256, 0, stream>>>(pos, sposW, soidxW, cstartW, bboxW,
                                                wts, Wc, W1, W2, wbfW, WcTW, W1TW, W2TW);
    knn_mlp_kernel<<<1536, 256, 0, stream>>>(sposW, soidxW, cstartW, bboxW, idxW, kerW, denW,
                                             wbfW, wts, pos, W1TW, b1, W2TW, b2, out_pos, out_w);
    conv_ln_kernel<<<512, 256, 0, stream>>>(wbfW, idxW, kerW, WcTW, bc, gamma, beta, ynbW);
    sample_kernel<<<512, 256, 0, stream>>>(ynbW, idxW, kerW, denW, out_s);
}

// Round 13
// 170.333 us; speedup vs baseline: 2.9684x; 1.1497x over previous
//
#include <hip/hip_runtime.h>
#include <math.h>

#define NTOT   32768
#define NSCN   16
#define NPS    2048
#define KK     16
#define CD     128
#define HD     256
#define GC     48      // grid cells per axis

typedef __attribute__((ext_vector_type(8))) short short8v;   // bf16x8 MFMA frag
typedef __attribute__((ext_vector_type(4))) float f32x4;     // MFMA accumulator
typedef unsigned long long u64;

__device__ __forceinline__ ushort f2bf(float f) {            // RNE f32->bf16
    uint u = __float_as_uint(f);
    u += 0x7FFFu + ((u >> 16) & 1u);
    return (ushort)(u >> 16);
}
__device__ __forceinline__ float bf2f(ushort h) {
    return __uint_as_float(((uint)h) << 16);
}

// ---------------------------------------------------------------------------
// K1: fused grid build (blocks 0..15, counting sort per scene) + prep
// (blocks 16.., w->bf16 and transposed bf16 weights, grid-stride).
// ---------------------------------------------------------------------------
__global__ __launch_bounds__(256) void build_prep_kernel(
    const float* __restrict__ pos,
    float2* __restrict__ spos, int* __restrict__ soidx,
    int* __restrict__ cstart, float4* __restrict__ bboxg,
    const float* __restrict__ w, const float* __restrict__ Wc,
    const float* __restrict__ W1, const float* __restrict__ W2,
    ushort* __restrict__ wbf, ushort* __restrict__ WcT,
    ushort* __restrict__ W1T, ushort* __restrict__ W2T)
{
    __shared__ int hist[GC * GC];
    __shared__ int scan_[GC * GC];
    __shared__ int part[256];
    __shared__ float4 wred[4];
    __shared__ float4 bbS;

    if (blockIdx.x >= 16) {
        // ---- prep path ----
        const int n_wb = NTOT * CD;
        const int n_wc = CD * CD;
        const int n_w1 = HD * CD;
        const int n_w2 = 144 * HD;
        const int total = n_wb + n_wc + n_w1 + n_w2;
        const int stride = (gridDim.x - 16) * 256;
        for (int t = (blockIdx.x - 16) * 256 + threadIdx.x; t < total; t += stride) {
            if (t < n_wb) {
                wbf[t] = f2bf(w[t]);
            } else if (t < n_wb + n_wc) {
                const int e = t - n_wb; const int n = e >> 7, k = e & 127;
                WcT[e] = f2bf(Wc[k * CD + n]);
            } else if (t < n_wb + n_wc + n_w1) {
                const int e = t - n_wb - n_wc; const int n = e >> 7, k = e & 127;
                W1T[e] = f2bf(W1[k * HD + n]);
            } else {
                const int e = t - n_wb - n_wc - n_w1; const int n = e >> 8, k = e & 255;
                W2T[e] = (n < 130) ? f2bf(W2[k * 130 + n]) : (ushort)0;
            }
        }
        return;
    }

    // ---- grid build path (one block per scene) ----
    const int s = blockIdx.x;
    const float2* gp = (const float2*)pos + s * NPS;

    float xmn = 3e38f, xmx = -3e38f, ymn = 3e38f, ymx = -3e38f;
    for (int i = threadIdx.x; i < NPS; i += 256) {
        const float2 p = gp[i];
        xmn = fminf(xmn, p.x); xmx = fmaxf(xmx, p.x);
        ymn = fminf(ymn, p.y); ymx = fmaxf(ymx, p.y);
    }
#pragma unroll
    for (int off = 1; off < 64; off <<= 1) {
        xmn = fminf(xmn, __shfl_xor(xmn, off));
        xmx = fmaxf(xmx, __shfl_xor(xmx, off));
        ymn = fminf(ymn, __shfl_xor(ymn, off));
        ymx = fmaxf(ymx, __shfl_xor(ymx, off));
    }
    if ((threadIdx.x & 63) == 0) wred[threadIdx.x >> 6] = make_float4(xmn, xmx, ymn, ymx);
    __syncthreads();
    if (threadIdx.x == 0) {
        float a = wred[0].x, bx = wred[0].y, c = wred[0].z, d = wred[0].w;
        for (int i = 1; i < 4; ++i) {
            a = fminf(a, wred[i].x); bx = fmaxf(bx, wred[i].y);
            c = fminf(c, wred[i].z); d  = fmaxf(d, wred[i].w);
        }
        const float hx = fmaxf(bx - a, 1e-6f) * (1.0f / GC);
        const float hy = fmaxf(d - c, 1e-6f) * (1.0f / GC);
        bbS = make_float4(a, c, hx, hy);
        bboxg[s] = bbS;
    }
    __syncthreads();
    const float bxm = bbS.x, bym = bbS.y;
    const float ihx = 1.0f / bbS.z, ihy = 1.0f / bbS.w;

    for (int i = threadIdx.x; i < GC * GC; i += 256) hist[i] = 0;
    __syncthreads();
    for (int i = threadIdx.x; i < NPS; i += 256) {
        const float2 p = gp[i];
        int cx = (int)((p.x - bxm) * ihx); cx = cx < 0 ? 0 : (cx > GC - 1 ? GC - 1 : cx);
        int cy = (int)((p.y - bym) * ihy); cy = cy < 0 ? 0 : (cy > GC - 1 ? GC - 1 : cy);
        atomicAdd(&hist[cy * GC + cx], 1);
    }
    __syncthreads();
    // ---- exclusive prefix (2304 = 256 threads x 9) ----
    {
        const int base = threadIdx.x * 9;
        int run = 0;
#pragma unroll
        for (int j = 0; j < 9; ++j) run += hist[base + j];
        part[threadIdx.x] = run;
        __syncthreads();
        if (threadIdx.x == 0) {
            int acc = 0;
            for (int t = 0; t < 256; ++t) { const int v = part[t]; part[t] = acc; acc += v; }
        }
        __syncthreads();
        run = part[threadIdx.x];
#pragma unroll
        for (int j = 0; j < 9; ++j) { const int h = hist[base + j]; scan_[base + j] = run; run += h; }
    }
    __syncthreads();
    for (int i = threadIdx.x; i < GC * GC; i += 256) cstart[s * (GC * GC + 1) + i] = scan_[i];
    if (threadIdx.x == 0) cstart[s * (GC * GC + 1) + GC * GC] = NPS;
    __syncthreads();
    for (int i = threadIdx.x; i < NPS; i += 256) {
        const float2 p = gp[i];
        int cx = (int)((p.x - bxm) * ihx); cx = cx < 0 ? 0 : (cx > GC - 1 ? GC - 1 : cx);
        int cy = (int)((p.y - bym) * ihy); cy = cy < 0 ? 0 : (cy > GC - 1 ? GC - 1 : cy);
        const int d = atomicAdd(&scan_[cy * GC + cx], 1);
        spos[s * NPS + d] = p;
        soidx[s * NPS + d] = i;
    }
}

// ---------------------------------------------------------------------------
// K2: fused exact-KNN + MLP (MFMA), 2:1 interleave. [R11 skeleton]
// KNN: value-only u32 top-16 scan + exact count stop; bitonic octet
// value-merge -> T = exact joint 16th d2; recovery re-scan (d2<=T) builds
// per-lane (d2,idx) survivor lists. n==16 (no ties, ~always): octet prefix
// scan -> DIRECT slot emission (selection-free; k-order is free since all
// consumers are permutation-invariant sums). Ties (n!=16): R11-proven
// 3-level u64 merge fallback -> exact jax-stable top-16.
// ---------------------------------------------------------------------------
__global__ __launch_bounds__(256, 4) void knn_mlp_kernel(
    const float2* __restrict__ spos, const int* __restrict__ soidx,
    const int* __restrict__ cstart, const float4* __restrict__ bboxg,
    int* __restrict__ idx_out, float* __restrict__ ker_out, float* __restrict__ den_out,
    const ushort* __restrict__ wbf, const float* __restrict__ w, const float* __restrict__ pos,
    const ushort* __restrict__ W1T, const float* __restrict__ b1,
    const ushort* __restrict__ W2T, const float* __restrict__ b2,
    float* __restrict__ out_pos, float* __restrict__ out_w)
{
    __shared__ __align__(16) char smem[33800];
    const int b = blockIdx.x;
    const int m3 = b % 3;

    if (m3 < 2) {
        // =================== KNN path ===================
        const int kb = (b / 3) * 2 + m3;           // 0..1023
        float2* sp  = (float2*)smem;               // 16384 B
        int*    oix = (int*)(smem + 16384);        // 8192 B
        int*    cs  = (int*)(smem + 24576);        // (GC*GC+1)*4 = 9220 B
        const int scene = kb >> 6;                 // 64 blocks per scene
        const int sbase = scene * NPS;
        for (int i = threadIdx.x; i < NPS; i += 256) { sp[i] = spos[sbase + i]; oix[i] = soidx[sbase + i]; }
        for (int i = threadIdx.x; i < GC * GC + 1; i += 256) cs[i] = cstart[scene * (GC * GC + 1) + i];
        __syncthreads();

        const float4 bb = bboxg[scene];
        const float ihx = 1.0f / bb.z, ihy = 1.0f / bb.w;
        const int p = threadIdx.x >> 3;            // query slot 0..31
        const int r = threadIdx.x & 7;             // octet lane
        const int qi = (kb & 63) * 32 + p;         // sorted-order point index
        const float2 my = sp[qi];
        int cx = (int)((my.x - bb.x) * ihx); cx = cx < 0 ? 0 : (cx > GC - 1 ? GC - 1 : cx);
        int cy = (int)((my.y - bb.y) * ihy); cy = cy < 0 ? 0 : (cy > GC - 1 ? GC - 1 : cy);

        uint key[16];
#pragma unroll
        for (int s_ = 0; s_ < 16; ++s_) key[s_] = 0xFFFFFFFFu;

        // value-only scan body: sorted-16 min/max chain (no index tracking)
#define SCANV(E) { \
    const float2 c2 = sp[E]; \
    const float ddx = c2.x - my.x, ddy = c2.y - my.y; \
    const float d2 = __fadd_rn(__fmul_rn(ddx, ddx), __fmul_rn(ddy, ddy)); \
    uint v_ = __float_as_uint(d2); \
    if (v_ < key[15]) { \
        _Pragma("unroll") \
        for (int s_ = 0; s_ < 16; ++s_) { \
            const uint lo_ = min(key[s_], v_); v_ = max(key[s_], v_); key[s_] = lo_; } \
    } }

        // ---- initial square R=1, rank-balanced 8 ways ----
        int xl = cx - 1 < 0 ? 0 : cx - 1, xh = cx + 1 > GC - 1 ? GC - 1 : cx + 1;
        int yl = cy - 1 < 0 ? 0 : cy - 1, yh = cy + 1 > GC - 1 ? GC - 1 : cy + 1;
        {
            int c = 0;
            for (int y = yl + r; y <= yh; y += 8) c += cs[y * GC + xh + 1] - cs[y * GC + xl];
            c += __shfl_xor(c, 1); c += __shfl_xor(c, 2); c += __shfl_xor(c, 4);
            const int t0 = (r * c) >> 3, t1 = ((r + 1) * c) >> 3;
            if (t0 < t1) {
                int y = yl, acc = 0;
                int rowc = cs[y * GC + xh + 1] - cs[y * GC + xl];
                while (acc + rowc <= t0) { acc += rowc; ++y; rowc = cs[y * GC + xh + 1] - cs[y * GC + xl]; }
                int e = cs[y * GC + xl] + (t0 - acc), eend = cs[y * GC + xh + 1];
                for (int t = t0; t < t1; ++t) {
                    while (e >= eend) { ++y; e = cs[y * GC + xl]; eend = cs[y * GC + xh + 1]; }
                    SCANV(e); ++e;
                }
            }
        }

        // ---- expansion: exact count stop; rows halved, cols by parity ----
        int R = 1;
        while (true) {
            if (xl == 0 && yl == 0 && xh == GC - 1 && yh == GC - 1) break;
            const float px = my.x - bb.x, py = my.y - bb.y;
            float g = 3e38f;
            if (xl > 0)      g = fminf(g, px - (float)xl * bb.z);
            if (xh < GC - 1) g = fminf(g, (float)(xh + 1) * bb.z - px);
            if (yl > 0)      g = fminf(g, py - (float)yl * bb.w);
            if (yh < GC - 1) g = fminf(g, (float)(yh + 1) * bb.w - py);
            g -= 1e-4f;                             // margin >> binning fp error
            if (g > 0.f) {
                const uint ggb = __float_as_uint(g * g);
                int c16 = 0;
#pragma unroll
                for (int s_ = 0; s_ < 16; ++s_) c16 += (key[s_] <= ggb) ? 1 : 0;
                c16 += __shfl_xor(c16, 1); c16 += __shfl_xor(c16, 2); c16 += __shfl_xor(c16, 4);
                if (c16 >= 16) break;               // exact: >=16 true cands within g
            }
            ++R;
            const int nxl = cx - R < 0 ? 0 : cx - R, nxh = cx + R > GC - 1 ? GC - 1 : cx + R;
            const int nyl = cy - R < 0 ? 0 : cy - R, nyh = cy + R > GC - 1 ? GC - 1 : cy + R;
            if (r < 4) {                            // new top/bottom row, halved by rank
                const int y = (r < 2) ? cy - R : cy + R;
                if (y >= 0 && y <= GC - 1) {
                    const int e0 = cs[y * GC + nxl], e1 = cs[y * GC + nxh + 1];
                    const int n = e1 - e0, h = r & 1;
                    const int es = e0 + ((n * h) >> 1), ee = e0 + ((n * (h + 1)) >> 1);
                    for (int e = es; e < ee; ++e) SCANV(e);
                }
            } else {                                // new left/right col, y-parity split
                const int x = (r < 6) ? cx - R : cx + R;
                if (x >= 0 && x <= GC - 1) {
                    const int ylc = nyl + ((cy - R >= 0) ? 1 : 0);
                    const int yhc = nyh - ((cy + R <= GC - 1) ? 1 : 0);
                    for (int y = ylc + (r & 1); y <= yhc; y += 2) {
                        const int c0 = y * GC + x;
                        const int e1_ = cs[c0 + 1];
                        for (int e = cs[c0]; e < e1_; ++e) SCANV(e);
                    }
                }
            }
            xl = nxl; xh = nxh; yl = nyl; yh = nyh;
        }
#undef SCANV

        // ---- bitonic octet value-merge: joint sorted 16 smallest d2 ----
#pragma unroll
        for (int lvl = 1; lvl <= 4; lvl <<= 1) {
            uint bv[16];
#pragma unroll
            for (int s_ = 0; s_ < 16; ++s_) bv[s_] = (uint)__shfl_xor((int)key[s_], lvl);
            uint t[16];
#pragma unroll
            for (int i = 0; i < 16; ++i) t[i] = min(key[i], bv[15 - i]);   // lower half
#pragma unroll
            for (int d = 8; d >= 1; d >>= 1) {                             // bitonic clean
#pragma unroll
                for (int i = 0; i < 16; ++i) {
                    if ((i & d) == 0) {
                        const uint lo = min(t[i], t[i + d]);
                        t[i + d] = max(t[i], t[i + d]);
                        t[i] = lo;
                    }
                }
            }
#pragma unroll
            for (int s_ = 0; s_ < 16; ++s_) key[s_] = t[s_];
        }
        const uint T = key[15];                     // exact joint 16th distance

        // ---- recovery re-scan of final square: d2<=T -> per-lane (d2,idx) ----
        u64 k64[16];
#pragma unroll
        for (int s_ = 0; s_ < 16; ++s_) k64[s_] = ~0ULL;
        int nloc = 0;                               // uncapped survivor count
        {
            int c = 0;
            for (int y = yl + r; y <= yh; y += 8) c += cs[y * GC + xh + 1] - cs[y * GC + xl];
            c += __shfl_xor(c, 1); c += __shfl_xor(c, 2); c += __shfl_xor(c, 4);
            const int t0 = (r * c) >> 3, t1 = ((r + 1) * c) >> 3;
            if (t0 < t1) {
                int y = yl, acc = 0;
                int rowc = cs[y * GC + xh + 1] - cs[y * GC + xl];
                while (acc + rowc <= t0) { acc += rowc; ++y; rowc = cs[y * GC + xh + 1] - cs[y * GC + xl]; }
                int e = cs[y * GC + xl] + (t0 - acc), eend = cs[y * GC + xh + 1];
                for (int t = t0; t < t1; ++t) {
                    while (e >= eend) { ++y; e = cs[y * GC + xl]; eend = cs[y * GC + xh + 1]; }
                    const float2 c2 = sp[e];
                    const float ddx = c2.x - my.x, ddy = c2.y - my.y;
                    const float d2 = __fadd_rn(__fmul_rn(ddx, ddx), __fmul_rn(ddy, ddy));
                    const uint d2b = __float_as_uint(d2);
                    if (d2b <= T) {                 // exact top-16 member (or tie)
                        ++nloc;
                        u64 ck = (((u64)d2b) << 32) | (uint)oix[e];
                        if (ck < k64[15]) {
#pragma unroll
                            for (int s_ = 0; s_ < 16; ++s_) {
                                const bool sm_ = ck < k64[s_]; const u64 o_ = k64[s_];
                                k64[s_] = sm_ ? ck : o_; ck = sm_ ? o_ : ck;
                            }
                        }
                    }
                    ++e;
                }
            }
        }

        // ---- octet exclusive prefix of survivor counts ----
        int incl = nloc;
#pragma unroll
        for (int d = 1; d < 8; d <<= 1) {
            const int v = __shfl_up(incl, d, 8);
            if (r >= d) incl += v;
        }
        const int ntot = __shfl(incl, 7, 8);
        const int off  = incl - nloc;
        const int gq = sbase + oix[qi];             // output row = ORIGINAL index

        if (ntot == 16) {
            // ---- fast path: selection-free direct emission (order is free) ----
            float den = 0.f;
            for (int i = 0; i < nloc; ++i) {
                const u64 e = k64[i];
                const float d2 = __uint_as_float((uint)(e >> 32));
                const float kv = expf(-2.0f * d2);
                idx_out[gq * KK + off + i] = sbase + (int)(e & 0xFFFFFFFFULL);
                ker_out[gq * KK + off + i] = kv;
                den += kv;
            }
            den += __shfl_xor(den, 1); den += __shfl_xor(den, 2); den += __shfl_xor(den, 4);
            if (r == 0) den_out[gq] = den;
        } else {
            // ---- tie fallback (~never): R11-proven 3-level u64 merge ----
#pragma unroll
            for (int lvl = 1; lvl <= 4; lvl <<= 1) {
                u64 tmp[16];
#pragma unroll
                for (int s_ = 0; s_ < 16; ++s_) {
                    const uint lo = (uint)__shfl_xor((int)(uint)(k64[s_] & 0xFFFFFFFFULL), lvl);
                    const uint hi = (uint)__shfl_xor((int)(uint)(k64[s_] >> 32), lvl);
                    tmp[s_] = (((u64)hi) << 32) | lo;
                }
#pragma unroll
                for (int s_ = 0; s_ < 16; ++s_) {
                    u64 ck = tmp[s_];
                    if (ck < k64[15]) {
#pragma unroll
                        for (int t2 = 0; t2 < 16; ++t2) {
                            const bool sm = ck < k64[t2];
                            const u64 o = k64[t2];
                            k64[t2] = sm ? ck : o;
                            ck      = sm ? o  : ck;
                        }
                    }
                }
            }
            if (r == 0) {
                int iv[16]; float kv[16]; float den = 0.f;
#pragma unroll
                for (int s_ = 0; s_ < 16; ++s_) {
                    const float d2 = __uint_as_float((uint)(k64[s_] >> 32));
                    kv[s_] = expf(-2.0f * d2);
                    den += kv[s_];
                    iv[s_] = sbase + (int)(k64[s_] & 0xFFFFFFFFULL);
                }
                int4*   ip4 = (int4*)(idx_out + gq * KK);
                float4* kp4 = (float4*)(ker_out + gq * KK);
#pragma unroll
                for (int s_ = 0; s_ < 4; ++s_) {
                    ip4[s_] = make_int4(iv[4*s_], iv[4*s_+1], iv[4*s_+2], iv[4*s_+3]);
                    kp4[s_] = make_float4(kv[4*s_], kv[4*s_+1], kv[4*s_+2], kv[4*s_+3]);
                }
                den_out[gq] = den;
            }
        }
        return;
    }

    // =================== MLP path ===================
    {
        const int mb = b / 3;                      // 0..511
        char* hS = smem;                           // 64 rows x 256 bf16 = 32 KB
        const int l = threadIdx.x & 63, wave = threadIdx.x >> 6;
        const int a = l & 15, g = l >> 4;
        const int m0 = wave * 16;
        const int rbase = mb * 64;
        const f32x4 z4 = {0.f, 0.f, 0.f, 0.f};

        f32x4 acc1[16];
#pragma unroll
        for (int nt = 0; nt < 16; ++nt) acc1[nt] = z4;
#pragma unroll
        for (int ks = 0; ks < 4; ++ks) {
            const short8v av = *(const short8v*)(wbf + (size_t)(rbase + m0 + a) * CD + ks * 32 + g * 8);
#pragma unroll
            for (int nt = 0; nt < 16; ++nt) {
                const short8v bv = *(const short8v*)(W1T + (nt * 16 + a) * CD + ks * 32 + g * 8);
                acc1[nt] = __builtin_amdgcn_mfma_f32_16x16x32_bf16(av, bv, acc1[nt], 0, 0, 0);
            }
        }
#pragma unroll
        for (int nt = 0; nt < 16; ++nt) {
            const float b1v = b1[nt * 16 + a];
#pragma unroll
            for (int rr = 0; rr < 4; ++rr) {
                const float hv = fmaxf(acc1[nt][rr] + b1v, 0.f);
                const int row = m0 + 4 * g + rr;
                int byte = row * 512 + (nt * 16 + a) * 2;
                byte ^= ((row & 7) << 4);
                *(ushort*)(hS + byte) = f2bf(hv);
            }
        }
        __syncthreads();

        f32x4 acc2[9];
#pragma unroll
        for (int nt = 0; nt < 9; ++nt) acc2[nt] = z4;
#pragma unroll
        for (int ks = 0; ks < 8; ++ks) {
            const int row = m0 + a;
            int byte = row * 512 + (ks * 32 + g * 8) * 2;
            byte ^= ((row & 7) << 4);
            const short8v av = *(const short8v*)(hS + byte);
#pragma unroll
            for (int nt = 0; nt < 9; ++nt) {
                const short8v bv = *(const short8v*)(W2T + (nt * 16 + a) * HD + ks * 32 + g * 8);
                acc2[nt] = __builtin_amdgcn_mfma_f32_16x16x32_bf16(av, bv, acc2[nt], 0, 0, 0);
            }
        }
#pragma unroll
        for (int nt = 0; nt < 9; ++nt) {
            const int col = nt * 16 + a;
            const float b2v = (col < 130) ? b2[col] : 0.f;
#pragma unroll
            for (int rr = 0; rr < 4; ++rr) {
                const int rowg = rbase + m0 + 4 * g + rr;
                const float dv = acc2[nt][rr] + b2v;
                if (col >= 2 && col < 130) {
                    out_w[(size_t)rowg * CD + (col - 2)] = w[(size_t)rowg * CD + (col - 2)] + dv;
                } else if (col == 0) {
                    out_pos[rowg * 2] = pos[rowg * 2] + dv;
                } else if (col == 1) {
                    out_pos[rowg * 2 + 1] = pos[rowg * 2 + 1] + dv;
                }
            }
        }
    }
}

// ---------------------------------------------------------------------------
// conv+LN: gather-aggregate (bf16) -> swizzled LDS -> MFMA mix -> LN -> yn bf16
// ---------------------------------------------------------------------------
__global__ __launch_bounds__(256) void conv_ln_kernel(
    const ushort* __restrict__ wbf, const int* __restrict__ idx, const float* __restrict__ ker,
    const ushort* __restrict__ WcT, const float* __restrict__ bc,
    const float* __restrict__ gamma, const float* __restrict__ beta,
    ushort* __restrict__ ynb)
{
    __shared__ char aggS[64 * 256];                 // 64 rows x 128 bf16
    {
        const int p = threadIdx.x >> 2, q = threadIdx.x & 3;
        const int i = blockIdx.x * 64 + p;
        const int*   ip = idx + i * KK;
        const float* kp = ker + i * KK;
        float acc[32];
#pragma unroll
        for (int e = 0; e < 32; ++e) acc[e] = 0.f;
#pragma unroll 4
        for (int k = 0; k < KK; ++k) {
            const int j = ip[k];
            const float kv = kp[k];
            const ushort* rp = wbf + (size_t)j * CD + q * 32;
#pragma unroll
            for (int jj = 0; jj < 4; ++jj) {
                const short8v v = *(const short8v*)(rp + jj * 8);
#pragma unroll
                for (int e = 0; e < 8; ++e)
                    acc[jj * 8 + e] += kv * bf2f((ushort)v[e]);
            }
        }
#pragma unroll
        for (int jj = 0; jj < 4; ++jj) {
            short8v pack;
#pragma unroll
            for (int e = 0; e < 8; ++e) pack[e] = (short)f2bf(acc[jj * 8 + e]);
            int byte = p * 256 + q * 64 + jj * 16;
            byte ^= ((p & 7) << 4);
            *(short8v*)(aggS + byte) = pack;
        }
    }
    __syncthreads();

    const int l = threadIdx.x & 63, wave = threadIdx.x >> 6;
    const int a = l & 15, g = l >> 4;
    const int m0 = wave * 16;
    const f32x4 z4 = {0.f, 0.f, 0.f, 0.f};
    f32x4 accc[8];
#pragma unroll
    for (int nt = 0; nt < 8; ++nt) accc[nt] = z4;
#pragma unroll
    for (int ks = 0; ks < 4; ++ks) {
        const int row = m0 + a;
        int byte = row * 256 + ks * 64 + g * 16;
        byte ^= ((row & 7) << 4);
        const short8v av = *(const short8v*)(aggS + byte);
#pragma unroll
        for (int nt = 0; nt < 8; ++nt) {
            const short8v bv = *(const short8v*)(WcT + (nt * 16 + a) * CD + ks * 32 + g * 8);
            accc[nt] = __builtin_amdgcn_mfma_f32_16x16x32_bf16(av, bv, accc[nt], 0, 0, 0);
        }
    }
    float bcv[8], gv[8], btv[8];
#pragma unroll
    for (int nt = 0; nt < 8; ++nt) {
        bcv[nt] = bc[nt * 16 + a];
        gv[nt]  = gamma[nt * 16 + a];
        btv[nt] = beta[nt * 16 + a];
    }
#pragma unroll
    for (int r = 0; r < 4; ++r) {
        float s = 0.f;
#pragma unroll
        for (int nt = 0; nt < 8; ++nt) s += accc[nt][r] + bcv[nt];
        s += __shfl_xor(s, 1); s += __shfl_xor(s, 2); s += __shfl_xor(s, 4); s += __shfl_xor(s, 8);
        const float mu = s * (1.f / 128.f);
        float v = 0.f;
#pragma unroll
        for (int nt = 0; nt < 8; ++nt) { const float t = accc[nt][r] + bcv[nt] - mu; v += t * t; }
        v += __shfl_xor(v, 1); v += __shfl_xor(v, 2); v += __shfl_xor(v, 4); v += __shfl_xor(v, 8);
        const float rs = rsqrtf(v * (1.f / 128.f) + 1e-5f);
        const int rowg = blockIdx.x * 64 + m0 + 4 * g + r;
#pragma unroll
        for (int nt = 0; nt < 8; ++nt) {
            const float o = (accc[nt][r] + bcv[nt] - mu) * rs * gv[nt] + btv[nt];
            ynb[(size_t)rowg * CD + nt * 16 + a] = f2bf(o);
        }
    }
}

// ---------------------------------------------------------------------------
// sample: sampled = (sum_k ker * yn_bf16[idx]) / den
// ---------------------------------------------------------------------------
__global__ __launch_bounds__(256) void sample_kernel(
    const ushort* __restrict__ ynb, const int* __restrict__ idx, const float* __restrict__ ker,
    const float* __restrict__ den, float* __restrict__ outS)
{
    const int p = threadIdx.x >> 2, q = threadIdx.x & 3;
    const int i = blockIdx.x * 64 + p;
    const int*   ip = idx + i * KK;
    const float* kp = ker + i * KK;
    float acc[32];
#pragma unroll
    for (int e = 0; e < 32; ++e) acc[e] = 0.f;
#pragma unroll 4
    for (int k = 0; k < KK; ++k) {
        const int j = ip[k];
        const float kv = kp[k];
        const ushort* rp = ynb + (size_t)j * CD + q * 32;
#pragma unroll
        for (int jj = 0; jj < 4; ++jj) {
            const short8v v = *(const short8v*)(rp + jj * 8);
#pragma unroll
            for (int e = 0; e < 8; ++e)
                acc[jj * 8 + e] += kv * bf2f((ushort)v[e]);
        }
    }
    const float inv = 1.0f / den[i];
    float* op = outS + (size_t)i * CD + q * 32;
#pragma unroll
    for (int jj = 0; jj < 8; ++jj)
        *(float4*)(op + jj * 4) = make_float4(acc[jj*4] * inv, acc[jj*4+1] * inv,
                                              acc[jj*4+2] * inv, acc[jj*4+3] * inv);
}

extern "C" void kernel_launch(void* const* d_in, const int* in_sizes, int n_in,
                              void* d_out, int out_size, void* d_ws, size_t ws_size,
                              hipStream_t stream)
{
    (void)in_sizes; (void)n_in; (void)out_size; (void)ws_size;
    const float* pos   = (const float*)d_in[0];
    const float* wts   = (const float*)d_in[1];
    // d_in[2] = batch (sorted, equal-sized) -> implicit: scene = i / 2048
    const float* Wc    = (const float*)d_in[3];
    const float* bc    = (const float*)d_in[4];
    const float* gamma = (const float*)d_in[5];
    const float* beta  = (const float*)d_in[6];
    const float* W1    = (const float*)d_in[7];
    const float* b1    = (const float*)d_in[8];
    const float* W2    = (const float*)d_in[9];
    const float* b2    = (const float*)d_in[10];

    float* out_pos = (float*)d_out;
    float* out_w   = out_pos + NTOT * 2;
    float* out_s   = out_w + NTOT * CD;

    // workspace layout (bytes), total ~21.9 MB
    char* wsb = (char*)d_ws;
    int*    idxW    = (int*)(wsb);                               // 2 MB
    float*  kerW    = (float*)(wsb + 2097152);                   // 2 MB
    float*  denW    = (float*)(wsb + 4194304);                   // 128 KB
    ushort* ynbW    = (ushort*)(wsb + 4325376);                  // 8 MB
    ushort* wbfW    = (ushort*)(wsb + 12713984);                 // 8 MB
    ushort* WcTW    = (ushort*)(wsb + 21102592);                 // 32 KB
    ushort* W1TW    = (ushort*)(wsb + 21135360);                 // 64 KB
    ushort* W2TW    = (ushort*)(wsb + 21200896);                 // 72 KB
    float2* sposW   = (float2*)(wsb + 21274624);                 // 256 KB
    int*    soidxW  = (int*)(wsb + 21536768);                    // 128 KB
    int*    cstartW = (int*)(wsb + 21667840);                    // (48*48+1)*16*4 B
    float4* bboxW   = (float4*)(wsb + 21815360);                 // 256 B

    build_prep_kernel<<<1040, 256, 0, stream>>>(pos, sposW, soidxW, cstartW, bboxW,
                                                wts, Wc, W1, W2, wbfW, WcTW, W1TW, W2TW);
    knn_mlp_kernel<<<1536, 256, 0, stream>>>(sposW, soidxW, cstartW, bboxW, idxW, kerW, denW,
                                             wbfW, wts, pos, W1TW, b1, W2TW, b2, out_pos, out_w);
    conv_ln_kernel<<<512, 256, 0, stream>>>(wbfW, idxW, kerW, WcTW, bc, gamma, beta, ynbW);
    sample_kernel<<<512, 256, 0, stream>>>(ynbW, idxW, kerW, denW, out_s);
}

// Round 14
// 154.757 us; speedup vs baseline: 3.2672x; 1.1006x over previous
//
#include <hip/hip_runtime.h>
#include <math.h>

#define NTOT   32768
#define NSCN   16
#define NPS    2048
#define KK     16
#define CD     128
#define HD     256
#define GC     48      // grid cells per axis

typedef __attribute__((ext_vector_type(8))) short short8v;   // bf16x8 MFMA frag
typedef __attribute__((ext_vector_type(4))) float f32x4;     // MFMA accumulator
typedef unsigned long long u64;

__device__ __forceinline__ ushort f2bf(float f) {            // RNE f32->bf16
    uint u = __float_as_uint(f);
    u += 0x7FFFu + ((u >> 16) & 1u);
    return (ushort)(u >> 16);
}
__device__ __forceinline__ float bf2f(ushort h) {
    return __uint_as_float(((uint)h) << 16);
}

// ---------------------------------------------------------------------------
// K1: fused grid build (blocks 0..15, counting sort per scene) + prep
// (blocks 16.., w->bf16 and transposed bf16 weights, grid-stride).
// ---------------------------------------------------------------------------
__global__ __launch_bounds__(256) void build_prep_kernel(
    const float* __restrict__ pos,
    float2* __restrict__ spos, int* __restrict__ soidx,
    int* __restrict__ cstart, float4* __restrict__ bboxg,
    const float* __restrict__ w, const float* __restrict__ Wc,
    const float* __restrict__ W1, const float* __restrict__ W2,
    ushort* __restrict__ wbf, ushort* __restrict__ WcT,
    ushort* __restrict__ W1T, ushort* __restrict__ W2T)
{
    __shared__ int hist[GC * GC];
    __shared__ int scan_[GC * GC];
    __shared__ int part[256];
    __shared__ float4 wred[4];
    __shared__ float4 bbS;

    if (blockIdx.x >= 16) {
        // ---- prep path ----
        const int n_wb = NTOT * CD;
        const int n_wc = CD * CD;
        const int n_w1 = HD * CD;
        const int n_w2 = 144 * HD;
        const int total = n_wb + n_wc + n_w1 + n_w2;
        const int stride = (gridDim.x - 16) * 256;
        for (int t = (blockIdx.x - 16) * 256 + threadIdx.x; t < total; t += stride) {
            if (t < n_wb) {
                wbf[t] = f2bf(w[t]);
            } else if (t < n_wb + n_wc) {
                const int e = t - n_wb; const int n = e >> 7, k = e & 127;
                WcT[e] = f2bf(Wc[k * CD + n]);
            } else if (t < n_wb + n_wc + n_w1) {
                const int e = t - n_wb - n_wc; const int n = e >> 7, k = e & 127;
                W1T[e] = f2bf(W1[k * HD + n]);
            } else {
                const int e = t - n_wb - n_wc - n_w1; const int n = e >> 8, k = e & 255;
                W2T[e] = (n < 130) ? f2bf(W2[k * 130 + n]) : (ushort)0;
            }
        }
        return;
    }

    // ---- grid build path (one block per scene) ----
    const int s = blockIdx.x;
    const float2* gp = (const float2*)pos + s * NPS;

    float xmn = 3e38f, xmx = -3e38f, ymn = 3e38f, ymx = -3e38f;
    for (int i = threadIdx.x; i < NPS; i += 256) {
        const float2 p = gp[i];
        xmn = fminf(xmn, p.x); xmx = fmaxf(xmx, p.x);
        ymn = fminf(ymn, p.y); ymx = fmaxf(ymx, p.y);
    }
#pragma unroll
    for (int off = 1; off < 64; off <<= 1) {
        xmn = fminf(xmn, __shfl_xor(xmn, off));
        xmx = fmaxf(xmx, __shfl_xor(xmx, off));
        ymn = fminf(ymn, __shfl_xor(ymn, off));
        ymx = fmaxf(ymx, __shfl_xor(ymx, off));
    }
    if ((threadIdx.x & 63) == 0) wred[threadIdx.x >> 6] = make_float4(xmn, xmx, ymn, ymx);
    __syncthreads();
    if (threadIdx.x == 0) {
        float a = wred[0].x, bx = wred[0].y, c = wred[0].z, d = wred[0].w;
        for (int i = 1; i < 4; ++i) {
            a = fminf(a, wred[i].x); bx = fmaxf(bx, wred[i].y);
            c = fminf(c, wred[i].z); d  = fmaxf(d, wred[i].w);
        }
        const float hx = fmaxf(bx - a, 1e-6f) * (1.0f / GC);
        const float hy = fmaxf(d - c, 1e-6f) * (1.0f / GC);
        bbS = make_float4(a, c, hx, hy);
        bboxg[s] = bbS;
    }
    __syncthreads();
    const float bxm = bbS.x, bym = bbS.y;
    const float ihx = 1.0f / bbS.z, ihy = 1.0f / bbS.w;

    for (int i = threadIdx.x; i < GC * GC; i += 256) hist[i] = 0;
    __syncthreads();
    for (int i = threadIdx.x; i < NPS; i += 256) {
        const float2 p = gp[i];
        int cx = (int)((p.x - bxm) * ihx); cx = cx < 0 ? 0 : (cx > GC - 1 ? GC - 1 : cx);
        int cy = (int)((p.y - bym) * ihy); cy = cy < 0 ? 0 : (cy > GC - 1 ? GC - 1 : cy);
        atomicAdd(&hist[cy * GC + cx], 1);
    }
    __syncthreads();
    // ---- exclusive prefix (2304 = 256 threads x 9) ----
    {
        const int base = threadIdx.x * 9;
        int run = 0;
#pragma unroll
        for (int j = 0; j < 9; ++j) run += hist[base + j];
        part[threadIdx.x] = run;
        __syncthreads();
        if (threadIdx.x == 0) {
            int acc = 0;
            for (int t = 0; t < 256; ++t) { const int v = part[t]; part[t] = acc; acc += v; }
        }
        __syncthreads();
        run = part[threadIdx.x];
#pragma unroll
        for (int j = 0; j < 9; ++j) { const int h = hist[base + j]; scan_[base + j] = run; run += h; }
    }
    __syncthreads();
    for (int i = threadIdx.x; i < GC * GC; i += 256) cstart[s * (GC * GC + 1) + i] = scan_[i];
    if (threadIdx.x == 0) cstart[s * (GC * GC + 1) + GC * GC] = NPS;
    __syncthreads();
    for (int i = threadIdx.x; i < NPS; i += 256) {
        const float2 p = gp[i];
        int cx = (int)((p.x - bxm) * ihx); cx = cx < 0 ? 0 : (cx > GC - 1 ? GC - 1 : cx);
        int cy = (int)((p.y - bym) * ihy); cy = cy < 0 ? 0 : (cy > GC - 1 ? GC - 1 : cy);
        const int d = atomicAdd(&scan_[cy * GC + cx], 1);
        spos[s * NPS + d] = p;
        soidx[s * NPS + d] = i;
    }
}

// ---------------------------------------------------------------------------
// K2: fused exact-KNN + MLP (MFMA), 2:1 interleave. [R12 skeleton]
// KNN: ADAPTIVE initial square (grow R ~1.5x until >=48 pts by cs[] row-count
// sums — no point scans) -> rank-balanced value-only scan -> exact count-stop
// ring expansion -> bitonic octet value-merge (T = exact joint 16th d2) ->
// recovery re-scan (d2<=T) -> prefix-scan direct emission (order-free).
// Ties (ntot!=16): R11-proven 3-level u64 merge fallback.
// ---------------------------------------------------------------------------
__global__ __launch_bounds__(256, 4) void knn_mlp_kernel(
    const float2* __restrict__ spos, const int* __restrict__ soidx,
    const int* __restrict__ cstart, const float4* __restrict__ bboxg,
    int* __restrict__ idx_out, float* __restrict__ ker_out, float* __restrict__ den_out,
    const ushort* __restrict__ wbf, const float* __restrict__ w, const float* __restrict__ pos,
    const ushort* __restrict__ W1T, const float* __restrict__ b1,
    const ushort* __restrict__ W2T, const float* __restrict__ b2,
    float* __restrict__ out_pos, float* __restrict__ out_w)
{
    __shared__ __align__(16) char smem[33800];
    const int b = blockIdx.x;
    const int m3 = b % 3;

    if (m3 < 2) {
        // =================== KNN path ===================
        const int kb = (b / 3) * 2 + m3;           // 0..1023
        float2* sp  = (float2*)smem;               // 16384 B
        int*    oix = (int*)(smem + 16384);        // 8192 B
        int*    cs  = (int*)(smem + 24576);        // (GC*GC+1)*4 = 9220 B
        const int scene = kb >> 6;                 // 64 blocks per scene
        const int sbase = scene * NPS;
        for (int i = threadIdx.x; i < NPS; i += 256) { sp[i] = spos[sbase + i]; oix[i] = soidx[sbase + i]; }
        for (int i = threadIdx.x; i < GC * GC + 1; i += 256) cs[i] = cstart[scene * (GC * GC + 1) + i];
        __syncthreads();

        const float4 bb = bboxg[scene];
        const float ihx = 1.0f / bb.z, ihy = 1.0f / bb.w;
        const int p = threadIdx.x >> 3;            // query slot 0..31
        const int r = threadIdx.x & 7;             // octet lane
        const int qi = (kb & 63) * 32 + p;         // sorted-order point index
        const float2 my = sp[qi];
        int cx = (int)((my.x - bb.x) * ihx); cx = cx < 0 ? 0 : (cx > GC - 1 ? GC - 1 : cx);
        int cy = (int)((my.y - bb.y) * ihy); cy = cy < 0 ? 0 : (cy > GC - 1 ? GC - 1 : cy);

        uint key[16];
#pragma unroll
        for (int s_ = 0; s_ < 16; ++s_) key[s_] = 0xFFFFFFFFu;

        // value-only scan body: sorted-16 min/max chain (no index tracking)
#define SCANV(E) { \
    const float2 c2 = sp[E]; \
    const float ddx = c2.x - my.x, ddy = c2.y - my.y; \
    const float d2 = __fadd_rn(__fmul_rn(ddx, ddx), __fmul_rn(ddy, ddy)); \
    uint v_ = __float_as_uint(d2); \
    if (v_ < key[15]) { \
        _Pragma("unroll") \
        for (int s_ = 0; s_ < 16; ++s_) { \
            const uint lo_ = min(key[s_], v_); v_ = max(key[s_], v_); key[s_] = lo_; } \
    } }

        // ---- adaptive initial square: grow R (~1.5x) until >=48 pts by counts ----
        int R = 1;
        int xl, xh, yl, yh;
        while (true) {
            xl = cx - R < 0 ? 0 : cx - R; xh = cx + R > GC - 1 ? GC - 1 : cx + R;
            yl = cy - R < 0 ? 0 : cy - R; yh = cy + R > GC - 1 ? GC - 1 : cy + R;
            int c = 0;
            for (int y = yl + r; y <= yh; y += 8) c += cs[y * GC + xh + 1] - cs[y * GC + xl];
            c += __shfl_xor(c, 1); c += __shfl_xor(c, 2); c += __shfl_xor(c, 4);
            const bool full = (xl == 0 && yl == 0 && xh == GC - 1 && yh == GC - 1);
            if (c >= 48 || full) break;
            R += (R >> 1) + 1;
        }

        // ---- rank-balanced value scan of the initial square ----
        {
            int c = 0;
            for (int y = yl + r; y <= yh; y += 8) c += cs[y * GC + xh + 1] - cs[y * GC + xl];
            c += __shfl_xor(c, 1); c += __shfl_xor(c, 2); c += __shfl_xor(c, 4);
            const int t0 = (r * c) >> 3, t1 = ((r + 1) * c) >> 3;
            if (t0 < t1) {
                int y = yl, acc = 0;
                int rowc = cs[y * GC + xh + 1] - cs[y * GC + xl];
                while (acc + rowc <= t0) { acc += rowc; ++y; rowc = cs[y * GC + xh + 1] - cs[y * GC + xl]; }
                int e = cs[y * GC + xl] + (t0 - acc), eend = cs[y * GC + xh + 1];
                for (int t = t0; t < t1; ++t) {
                    while (e >= eend) { ++y; e = cs[y * GC + xl]; eend = cs[y * GC + xh + 1]; }
                    SCANV(e); ++e;
                }
            }
        }

        // ---- expansion: exact count stop; rows halved, cols by parity ----
        while (true) {
            if (xl == 0 && yl == 0 && xh == GC - 1 && yh == GC - 1) break;
            const float px = my.x - bb.x, py = my.y - bb.y;
            float g = 3e38f;
            if (xl > 0)      g = fminf(g, px - (float)xl * bb.z);
            if (xh < GC - 1) g = fminf(g, (float)(xh + 1) * bb.z - px);
            if (yl > 0)      g = fminf(g, py - (float)yl * bb.w);
            if (yh < GC - 1) g = fminf(g, (float)(yh + 1) * bb.w - py);
            g -= 1e-4f;                             // margin >> binning fp error
            if (g > 0.f) {
                const uint ggb = __float_as_uint(g * g);
                int c16 = 0;
#pragma unroll
                for (int s_ = 0; s_ < 16; ++s_) c16 += (key[s_] <= ggb) ? 1 : 0;
                c16 += __shfl_xor(c16, 1); c16 += __shfl_xor(c16, 2); c16 += __shfl_xor(c16, 4);
                if (c16 >= 16) break;               // exact: >=16 true cands within g
            }
            ++R;
            const int nxl = cx - R < 0 ? 0 : cx - R, nxh = cx + R > GC - 1 ? GC - 1 : cx + R;
            const int nyl = cy - R < 0 ? 0 : cy - R, nyh = cy + R > GC - 1 ? GC - 1 : cy + R;
            if (r < 4) {                            // new top/bottom row, halved by rank
                const int y = (r < 2) ? cy - R : cy + R;
                if (y >= 0 && y <= GC - 1) {
                    const int e0 = cs[y * GC + nxl], e1 = cs[y * GC + nxh + 1];
                    const int n = e1 - e0, h = r & 1;
                    const int es = e0 + ((n * h) >> 1), ee = e0 + ((n * (h + 1)) >> 1);
                    for (int e = es; e < ee; ++e) SCANV(e);
                }
            } else {                                // new left/right col, y-parity split
                const int x = (r < 6) ? cx - R : cx + R;
                if (x >= 0 && x <= GC - 1) {
                    const int ylc = nyl + ((cy - R >= 0) ? 1 : 0);
                    const int yhc = nyh - ((cy + R <= GC - 1) ? 1 : 0);
                    for (int y = ylc + (r & 1); y <= yhc; y += 2) {
                        const int c0 = y * GC + x;
                        const int e1_ = cs[c0 + 1];
                        for (int e = cs[c0]; e < e1_; ++e) SCANV(e);
                    }
                }
            }
            xl = nxl; xh = nxh; yl = nyl; yh = nyh;
        }
#undef SCANV

        // ---- bitonic octet value-merge: joint sorted 16 smallest d2 ----
#pragma unroll
        for (int lvl = 1; lvl <= 4; lvl <<= 1) {
            uint bv[16];
#pragma unroll
            for (int s_ = 0; s_ < 16; ++s_) bv[s_] = (uint)__shfl_xor((int)key[s_], lvl);
            uint t[16];
#pragma unroll
            for (int i = 0; i < 16; ++i) t[i] = min(key[i], bv[15 - i]);   // lower half
#pragma unroll
            for (int d = 8; d >= 1; d >>= 1) {                             // bitonic clean
#pragma unroll
                for (int i = 0; i < 16; ++i) {
                    if ((i & d) == 0) {
                        const uint lo = min(t[i], t[i + d]);
                        t[i + d] = max(t[i], t[i + d]);
                        t[i] = lo;
                    }
                }
            }
#pragma unroll
            for (int s_ = 0; s_ < 16; ++s_) key[s_] = t[s_];
        }
        const uint T = key[15];                     // exact joint 16th distance

        // ---- recovery re-scan of final square: d2<=T -> per-lane (d2,idx) ----
        u64 k64[16];
#pragma unroll
        for (int s_ = 0; s_ < 16; ++s_) k64[s_] = ~0ULL;
        int nloc = 0;                               // uncapped survivor count
        {
            int c = 0;
            for (int y = yl + r; y <= yh; y += 8) c += cs[y * GC + xh + 1] - cs[y * GC + xl];
            c += __shfl_xor(c, 1); c += __shfl_xor(c, 2); c += __shfl_xor(c, 4);
            const int t0 = (r * c) >> 3, t1 = ((r + 1) * c) >> 3;
            if (t0 < t1) {
                int y = yl, acc = 0;
                int rowc = cs[y * GC + xh + 1] - cs[y * GC + xl];
                while (acc + rowc <= t0) { acc += rowc; ++y; rowc = cs[y * GC + xh + 1] - cs[y * GC + xl]; }
                int e = cs[y * GC + xl] + (t0 - acc), eend = cs[y * GC + xh + 1];
                for (int t = t0; t < t1; ++t) {
                    while (e >= eend) { ++y; e = cs[y * GC + xl]; eend = cs[y * GC + xh + 1]; }
                    const float2 c2 = sp[e];
                    const float ddx = c2.x - my.x, ddy = c2.y - my.y;
                    const float d2 = __fadd_rn(__fmul_rn(ddx, ddx), __fmul_rn(ddy, ddy));
                    const uint d2b = __float_as_uint(d2);
                    if (d2b <= T) {                 // exact top-16 member (or tie)
                        ++nloc;
                        u64 ck = (((u64)d2b) << 32) | (uint)oix[e];
                        if (ck < k64[15]) {
#pragma unroll
                            for (int s_ = 0; s_ < 16; ++s_) {
                                const bool sm_ = ck < k64[s_]; const u64 o_ = k64[s_];
                                k64[s_] = sm_ ? ck : o_; ck = sm_ ? o_ : ck;
                            }
                        }
                    }
                    ++e;
                }
            }
        }

        // ---- octet exclusive prefix of survivor counts ----
        int incl = nloc;
#pragma unroll
        for (int d = 1; d < 8; d <<= 1) {
            const int v = __shfl_up(incl, d, 8);
            if (r >= d) incl += v;
        }
        const int ntot = __shfl(incl, 7, 8);
        const int off  = incl - nloc;
        const int gq = sbase + oix[qi];             // output row = ORIGINAL index

        if (ntot == 16) {
            // ---- fast path: selection-free direct emission (order is free) ----
            float den = 0.f;
            for (int i = 0; i < nloc; ++i) {
                const u64 e = k64[i];
                const float d2 = __uint_as_float((uint)(e >> 32));
                const float kv = expf(-2.0f * d2);
                idx_out[gq * KK + off + i] = sbase + (int)(e & 0xFFFFFFFFULL);
                ker_out[gq * KK + off + i] = kv;
                den += kv;
            }
            den += __shfl_xor(den, 1); den += __shfl_xor(den, 2); den += __shfl_xor(den, 4);
            if (r == 0) den_out[gq] = den;
        } else {
            // ---- tie fallback (~never): R11-proven 3-level u64 merge ----
#pragma unroll
            for (int lvl = 1; lvl <= 4; lvl <<= 1) {
                u64 tmp[16];
#pragma unroll
                for (int s_ = 0; s_ < 16; ++s_) {
                    const uint lo = (uint)__shfl_xor((int)(uint)(k64[s_] & 0xFFFFFFFFULL), lvl);
                    const uint hi = (uint)__shfl_xor((int)(uint)(k64[s_] >> 32), lvl);
                    tmp[s_] = (((u64)hi) << 32) | lo;
                }
#pragma unroll
                for (int s_ = 0; s_ < 16; ++s_) {
                    u64 ck = tmp[s_];
                    if (ck < k64[15]) {
#pragma unroll
                        for (int t2 = 0; t2 < 16; ++t2) {
                            const bool sm = ck < k64[t2];
                            const u64 o = k64[t2];
                            k64[t2] = sm ? ck : o;
                            ck      = sm ? o  : ck;
                        }
                    }
                }
            }
            if (r == 0) {
                int iv[16]; float kv[16]; float den = 0.f;
#pragma unroll
                for (int s_ = 0; s_ < 16; ++s_) {
                    const float d2 = __uint_as_float((uint)(k64[s_] >> 32));
                    kv[s_] = expf(-2.0f * d2);
                    den += kv[s_];
                    iv[s_] = sbase + (int)(k64[s_] & 0xFFFFFFFFULL);
                }
                int4*   ip4 = (int4*)(idx_out + gq * KK);
                float4* kp4 = (float4*)(ker_out + gq * KK);
#pragma unroll
                for (int s_ = 0; s_ < 4; ++s_) {
                    ip4[s_] = make_int4(iv[4*s_], iv[4*s_+1], iv[4*s_+2], iv[4*s_+3]);
                    kp4[s_] = make_float4(kv[4*s_], kv[4*s_+1], kv[4*s_+2], kv[4*s_+3]);
                }
                den_out[gq] = den;
            }
        }
        return;
    }

    // =================== MLP path ===================
    {
        const int mb = b / 3;                      // 0..511
        char* hS = smem;                           // 64 rows x 256 bf16 = 32 KB
        const int l = threadIdx.x & 63, wave = threadIdx.x >> 6;
        const int a = l & 15, g = l >> 4;
        const int m0 = wave * 16;
        const int rbase = mb * 64;
        const f32x4 z4 = {0.f, 0.f, 0.f, 0.f};

        f32x4 acc1[16];
#pragma unroll
        for (int nt = 0; nt < 16; ++nt) acc1[nt] = z4;
#pragma unroll
        for (int ks = 0; ks < 4; ++ks) {
            const short8v av = *(const short8v*)(wbf + (size_t)(rbase + m0 + a) * CD + ks * 32 + g * 8);
#pragma unroll
            for (int nt = 0; nt < 16; ++nt) {
                const short8v bv = *(const short8v*)(W1T + (nt * 16 + a) * CD + ks * 32 + g * 8);
                acc1[nt] = __builtin_amdgcn_mfma_f32_16x16x32_bf16(av, bv, acc1[nt], 0, 0, 0);
            }
        }
#pragma unroll
        for (int nt = 0; nt < 16; ++nt) {
            const float b1v = b1[nt * 16 + a];
#pragma unroll
            for (int rr = 0; rr < 4; ++rr) {
                const float hv = fmaxf(acc1[nt][rr] + b1v, 0.f);
                const int row = m0 + 4 * g + rr;
                int byte = row * 512 + (nt * 16 + a) * 2;
                byte ^= ((row & 7) << 4);
                *(ushort*)(hS + byte) = f2bf(hv);
            }
        }
        __syncthreads();

        f32x4 acc2[9];
#pragma unroll
        for (int nt = 0; nt < 9; ++nt) acc2[nt] = z4;
#pragma unroll
        for (int ks = 0; ks < 8; ++ks) {
            const int row = m0 + a;
            int byte = row * 512 + (ks * 32 + g * 8) * 2;
            byte ^= ((row & 7) << 4);
            const short8v av = *(const short8v*)(hS + byte);
#pragma unroll
            for (int nt = 0; nt < 9; ++nt) {
                const short8v bv = *(const short8v*)(W2T + (nt * 16 + a) * HD + ks * 32 + g * 8);
                acc2[nt] = __builtin_amdgcn_mfma_f32_16x16x32_bf16(av, bv, acc2[nt], 0, 0, 0);
            }
        }
#pragma unroll
        for (int nt = 0; nt < 9; ++nt) {
            const int col = nt * 16 + a;
            const float b2v = (col < 130) ? b2[col] : 0.f;
#pragma unroll
            for (int rr = 0; rr < 4; ++rr) {
                const int rowg = rbase + m0 + 4 * g + rr;
                const float dv = acc2[nt][rr] + b2v;
                if (col >= 2 && col < 130) {
                    out_w[(size_t)rowg * CD + (col - 2)] = w[(size_t)rowg * CD + (col - 2)] + dv;
                } else if (col == 0) {
                    out_pos[rowg * 2] = pos[rowg * 2] + dv;
                } else if (col == 1) {
                    out_pos[rowg * 2 + 1] = pos[rowg * 2 + 1] + dv;
                }
            }
        }
    }
}

// ---------------------------------------------------------------------------
// conv+LN: gather-aggregate (bf16) -> swizzled LDS -> MFMA mix -> LN -> yn bf16
// ---------------------------------------------------------------------------
__global__ __launch_bounds__(256) void conv_ln_kernel(
    const ushort* __restrict__ wbf, const int* __restrict__ idx, const float* __restrict__ ker,
    const ushort* __restrict__ WcT, const float* __restrict__ bc,
    const float* __restrict__ gamma, const float* __restrict__ beta,
    ushort* __restrict__ ynb)
{
    __shared__ char aggS[64 * 256];                 // 64 rows x 128 bf16
    {
        const int p = threadIdx.x >> 2, q = threadIdx.x & 3;
        const int i = blockIdx.x * 64 + p;
        const int*   ip = idx + i * KK;
        const float* kp = ker + i * KK;
        float acc[32];
#pragma unroll
        for (int e = 0; e < 32; ++e) acc[e] = 0.f;
#pragma unroll 4
        for (int k = 0; k < KK; ++k) {
            const int j = ip[k];
            const float kv = kp[k];
            const ushort* rp = wbf + (size_t)j * CD + q * 32;
#pragma unroll
            for (int jj = 0; jj < 4; ++jj) {
                const short8v v = *(const short8v*)(rp + jj * 8);
#pragma unroll
                for (int e = 0; e < 8; ++e)
                    acc[jj * 8 + e] += kv * bf2f((ushort)v[e]);
            }
        }
#pragma unroll
        for (int jj = 0; jj < 4; ++jj) {
            short8v pack;
#pragma unroll
            for (int e = 0; e < 8; ++e) pack[e] = (short)f2bf(acc[jj * 8 + e]);
            int byte = p * 256 + q * 64 + jj * 16;
            byte ^= ((p & 7) << 4);
            *(short8v*)(aggS + byte) = pack;
        }
    }
    __syncthreads();

    const int l = threadIdx.x & 63, wave = threadIdx.x >> 6;
    const int a = l & 15, g = l >> 4;
    const int m0 = wave * 16;
    const f32x4 z4 = {0.f, 0.f, 0.f, 0.f};
    f32x4 accc[8];
#pragma unroll
    for (int nt = 0; nt < 8; ++nt) accc[nt] = z4;
#pragma unroll
    for (int ks = 0; ks < 4; ++ks) {
        const int row = m0 + a;
        int byte = row * 256 + ks * 64 + g * 16;
        byte ^= ((row & 7) << 4);
        const short8v av = *(const short8v*)(aggS + byte);
#pragma unroll
        for (int nt = 0; nt < 8; ++nt) {
            const short8v bv = *(const short8v*)(WcT + (nt * 16 + a) * CD + ks * 32 + g * 8);
            accc[nt] = __builtin_amdgcn_mfma_f32_16x16x32_bf16(av, bv, accc[nt], 0, 0, 0);
        }
    }
    float bcv[8], gv[8], btv[8];
#pragma unroll
    for (int nt = 0; nt < 8; ++nt) {
        bcv[nt] = bc[nt * 16 + a];
        gv[nt]  = gamma[nt * 16 + a];
        btv[nt] = beta[nt * 16 + a];
    }
#pragma unroll
    for (int r = 0; r < 4; ++r) {
        float s = 0.f;
#pragma unroll
        for (int nt = 0; nt < 8; ++nt) s += accc[nt][r] + bcv[nt];
        s += __shfl_xor(s, 1); s += __shfl_xor(s, 2); s += __shfl_xor(s, 4); s += __shfl_xor(s, 8);
        const float mu = s * (1.f / 128.f);
        float v = 0.f;
#pragma unroll
        for (int nt = 0; nt < 8; ++nt) { const float t = accc[nt][r] + bcv[nt] - mu; v += t * t; }
        v += __shfl_xor(v, 1); v += __shfl_xor(v, 2); v += __shfl_xor(v, 4); v += __shfl_xor(v, 8);
        const float rs = rsqrtf(v * (1.f / 128.f) + 1e-5f);
        const int rowg = blockIdx.x * 64 + m0 + 4 * g + r;
#pragma unroll
        for (int nt = 0; nt < 8; ++nt) {
            const float o = (accc[nt][r] + bcv[nt] - mu) * rs * gv[nt] + btv[nt];
            ynb[(size_t)rowg * CD + nt * 16 + a] = f2bf(o);
        }
    }
}

// ---------------------------------------------------------------------------
// sample: sampled = (sum_k ker * yn_bf16[idx]) / den
// ---------------------------------------------------------------------------
__global__ __launch_bounds__(256) void sample_kernel(
    const ushort* __restrict__ ynb, const int* __restrict__ idx, const float* __restrict__ ker,
    const float* __restrict__ den, float* __restrict__ outS)
{
    const int p = threadIdx.x >> 2, q = threadIdx.x & 3;
    const int i = blockIdx.x * 64 + p;
    const int*   ip = idx + i * KK;
    const float* kp = ker + i * KK;
    float acc[32];
#pragma unroll
    for (int e = 0; e < 32; ++e) acc[e] = 0.f;
#pragma unroll 4
    for (int k = 0; k < KK; ++k) {
        const int j = ip[k];
        const float kv = kp[k];
        const ushort* rp = ynb + (size_t)j * CD + q * 32;
#pragma unroll
        for (int jj = 0; jj < 4; ++jj) {
            const short8v v = *(const short8v*)(rp + jj * 8);
#pragma unroll
            for (int e = 0; e < 8; ++e)
                acc[jj * 8 + e] += kv * bf2f((ushort)v[e]);
        }
    }
    const float inv = 1.0f / den[i];
    float* op = outS + (size_t)i * CD + q * 32;
#pragma unroll
    for (int jj = 0; jj < 8; ++jj)
        *(float4*)(op + jj * 4) = make_float4(acc[jj*4] * inv, acc[jj*4+1] * inv,
                                              acc[jj*4+2] * inv, acc[jj*4+3] * inv);
}

extern "C" void kernel_launch(void* const* d_in, const int* in_sizes, int n_in,
                              void* d_out, int out_size, void* d_ws, size_t ws_size,
                              hipStream_t stream)
{
    (void)in_sizes; (void)n_in; (void)out_size; (void)ws_size;
    const float* pos   = (const float*)d_in[0];
    const float* wts   = (const float*)d_in[1];
    // d_in[2] = batch (sorted, equal-sized) -> implicit: scene = i / 2048
    const float* Wc    = (const float*)d_in[3];
    const float* bc    = (const float*)d_in[4];
    const float* gamma = (const float*)d_in[5];
    const float* beta  = (const float*)d_in[6];
    const float* W1    = (const float*)d_in[7];
    const float* b1    = (const float*)d_in[8];
    const float* W2    = (const float*)d_in[9];
    const float* b2    = (const float*)d_in[10];

    float* out_pos = (float*)d_out;
    float* out_w   = out_pos + NTOT * 2;
    float* out_s   = out_w + NTOT * CD;

    // workspace layout (bytes), total ~21.9 MB
    char* wsb = (char*)d_ws;
    int*    idxW    = (int*)(wsb);                               // 2 MB
    float*  kerW    = (float*)(wsb + 2097152);                   // 2 MB
    float*  denW    = (float*)(wsb + 4194304);                   // 128 KB
    ushort* ynbW    = (ushort*)(wsb + 4325376);                  // 8 MB
    ushort* wbfW    = (ushort*)(wsb + 12713984);                 // 8 MB
    ushort* WcTW    = (ushort*)(wsb + 21102592);                 // 32 KB
    ushort* W1TW    = (ushort*)(wsb + 21135360);                 // 64 KB
    ushort* W2TW    = (ushort*)(wsb + 21200896);                 // 72 KB
    float2* sposW   = (float2*)(wsb + 21274624);                 // 256 KB
    int*    soidxW  = (int*)(wsb + 21536768);                    // 128 KB
    int*    cstartW = (int*)(wsb + 21667840);                    // (48*48+1)*16*4 B
    float4* bboxW   = (float4*)(wsb + 21815360);                 // 256 B

    build_prep_kernel<<<1040, 256, 0, stream>>>(pos, sposW, soidxW, cstartW, bboxW,
                                                wts, Wc, W1, W2, wbfW, WcTW, W1TW, W2TW);
    knn_mlp_kernel<<<1536, 256, 0, stream>>>(sposW, soidxW, cstartW, bboxW, idxW, kerW, denW,
                                             wbfW, wts, pos, W1TW, b1, W2TW, b2, out_pos, out_w);
    conv_ln_kernel<<<512, 256, 0, stream>>>(wbfW, idxW, kerW, WcTW, bc, gamma, beta, ynbW);
    sample_kernel<<<512, 256, 0, stream>>>(ynbW, idxW, kerW, denW, out_s);
}